// Round 1
// baseline (1889.961 us; speedup 1.0000x reference)
//
#include <hip/hip_runtime.h>
#include <math.h>

// Problem constants (B=4, L=1024, D=1024, H=16, DK=64)
#define NB 4
#define NL 1024
#define ND 1024
#define NH 16
#define NDK 64

// ---------------------------------------------------------------------------
// Stage 1: projections.
// q_all[b,h,l,k] = query[b,l,:] @ wq[h,:,k] + bq[h,k]   (z = 0..15)
// k_all[b,h,l,k] = key  [b,l,:] @ wk[h,:,k] + bk[h,k]   (z = 16..31)
// v_proj[b,l,k]  = value[b,l,:] @ wv[:,k]   + bv[k]     (z = 32)
// Each slice is a [4096 x 1024] @ [1024 x 64] GEMM.
// block 256, grid (row_tiles=64, z=33). 64 rows x 64 cols per wg, 4x4/thread.
// ---------------------------------------------------------------------------
__global__ __launch_bounds__(256) void proj_kernel(
    const float* __restrict__ query, const float* __restrict__ key_in,
    const float* __restrict__ value,
    const float* __restrict__ wq, const float* __restrict__ bq,
    const float* __restrict__ wk, const float* __restrict__ bk,
    const float* __restrict__ wv, const float* __restrict__ bv,
    float* __restrict__ q_all, float* __restrict__ k_all,
    float* __restrict__ v_proj)
{
    const int t = threadIdx.x;
    const int row0 = blockIdx.x * 64;
    const int z = blockIdx.y;

    const float* A; const float* W; const float* bias; float* C;
    int h, nh;
    if (z < 16)      { A = query;  W = wq + (size_t)z*ND*NDK;      bias = bq + z*NDK;      C = q_all;  h = z;    nh = 16; }
    else if (z < 32) { A = key_in; W = wk + (size_t)(z-16)*ND*NDK; bias = bk + (z-16)*NDK; C = k_all;  h = z-16; nh = 16; }
    else             { A = value;  W = wv;                         bias = bv;              C = v_proj; h = 0;    nh = 1;  }

    __shared__ float At[64][84];   // [row][k], pad 84 (16B-aligned rows, 2-way banks)
    __shared__ float Wt[64][64];   // [k][col]

    const int r0 = (t >> 4) * 4;   // output row group within tile
    const int c0 = (t & 15) * 4;   // output col group

    float acc[4][4];
    #pragma unroll
    for (int i = 0; i < 4; ++i)
        #pragma unroll
        for (int j = 0; j < 4; ++j) acc[i][j] = 0.f;

    for (int kt = 0; kt < 16; ++kt) {
        const int k0 = kt * 64;
        __syncthreads();
        #pragma unroll
        for (int i = 0; i < 4; ++i) {
            int idx = t + 256 * i;
            int ar = idx >> 4;
            int kc = (idx & 15) * 4;
            float4 v = *(const float4*)&A[(size_t)(row0 + ar) * ND + k0 + kc];
            *(float4*)&At[ar][kc] = v;
        }
        #pragma unroll
        for (int i = 0; i < 4; ++i) {
            int idx = t + 256 * i;
            int wr = idx >> 4;
            int wc = (idx & 15) * 4;
            float4 v = *(const float4*)&W[(size_t)(k0 + wr) * NDK + wc];
            *(float4*)&Wt[wr][wc] = v;
        }
        __syncthreads();
        #pragma unroll
        for (int kk = 0; kk < 64; kk += 4) {
            float4 a[4], w[4];
            #pragma unroll
            for (int i = 0; i < 4; ++i) a[i] = *(const float4*)&At[r0 + i][kk];
            #pragma unroll
            for (int q = 0; q < 4; ++q) w[q] = *(const float4*)&Wt[kk + q][c0];
            #pragma unroll
            for (int i = 0; i < 4; ++i) {
                #pragma unroll
                for (int j = 0; j < 4; ++j) {
                    acc[i][j] += a[i].x * ((const float*)&w[0])[j]
                               + a[i].y * ((const float*)&w[1])[j]
                               + a[i].z * ((const float*)&w[2])[j]
                               + a[i].w * ((const float*)&w[3])[j];
                }
            }
        }
    }

    float4 bias4 = *(const float4*)&bias[c0];
    #pragma unroll
    for (int i = 0; i < 4; ++i) {
        int r = row0 + r0 + i;
        int bb = r >> 10;
        int l  = r & 1023;
        float4 o;
        o.x = acc[i][0] + bias4.x;
        o.y = acc[i][1] + bias4.y;
        o.z = acc[i][2] + bias4.z;
        o.w = acc[i][3] + bias4.w;
        *(float4*)&C[(((size_t)bb * nh + h) * NL + l) * NDK + c0] = o;
    }
}

// ---------------------------------------------------------------------------
// Stage 2: per (b, 8-row q block), loop over all 16 heads:
//   scores = q @ k^T * 0.125 ; softmax rows ; write attn[b,q,h,:] ;
//   acc += attn_row @ v_proj  -> head mean accumulated in registers.
// block 256, grid (L/8=128, B=4). LDS: 2KB q + 32KB scores + 16KB v = 50KB.
// ---------------------------------------------------------------------------
__global__ __launch_bounds__(256) void attn_kernel(
    const float* __restrict__ q_all, const float* __restrict__ k_all,
    const float* __restrict__ v_proj,
    float* __restrict__ attn, float* __restrict__ head_mean)
{
    const int t  = threadIdx.x;
    const int q0 = blockIdx.x * 8;
    const int b  = blockIdx.y;

    __shared__ float qt[8][64];
    __shared__ float sc[8][1024];
    __shared__ float vt[64][64];

    const int qloc = t >> 5;   // 0..7 : q row this thread owns for softmax/PV
    const int s    = t & 31;   // lane within row group
    const int c0   = s * 2;    // 2 output cols of DK

    float accx = 0.f, accy = 0.f;

    for (int h = 0; h < 16; ++h) {
        const size_t bh = ((size_t)b * 16 + h) * NL;
        __syncthreads();   // prior-iteration sc/qt readers done
        if (t < 128) {
            int qrow = t >> 4;
            int qc = (t & 15) * 4;
            *(float4*)&qt[qrow][qc] =
                *(const float4*)&q_all[(bh + q0 + qrow) * NDK + qc];
        }
        __syncthreads();

        // ---- scores: each thread computes 4 k-rows x 8 q-rows ----
        for (int ii = 0; ii < 4; ++ii) {
            int kr = t + 256 * ii;
            const float4* kp = (const float4*)&k_all[(bh + kr) * NDK];
            float4 kv[16];
            #pragma unroll
            for (int u = 0; u < 16; ++u) kv[u] = kp[u];
            #pragma unroll
            for (int q = 0; q < 8; ++q) {
                float dot = 0.f;
                #pragma unroll
                for (int u = 0; u < 16; ++u) {
                    float4 qv = *(const float4*)&qt[q][u * 4];
                    dot += qv.x * kv[u].x + qv.y * kv[u].y
                         + qv.z * kv[u].z + qv.w * kv[u].w;
                }
                sc[q][kr] = dot * 0.125f;
            }
        }
        __syncthreads();

        // ---- softmax: row qloc handled by 32 lanes ----
        float m = -1e30f;
        #pragma unroll
        for (int i = 0; i < 32; ++i) m = fmaxf(m, sc[qloc][s + 32 * i]);
        #pragma unroll
        for (int o = 16; o > 0; o >>= 1) m = fmaxf(m, __shfl_xor(m, o, 32));
        float sum = 0.f;
        #pragma unroll
        for (int i = 0; i < 32; ++i) {
            int idx = s + 32 * i;
            float e = expf(sc[qloc][idx] - m);
            sc[qloc][idx] = e;
            sum += e;
        }
        #pragma unroll
        for (int o = 16; o > 0; o >>= 1) sum += __shfl_xor(sum, o, 32);
        float inv = 1.0f / sum;
        #pragma unroll
        for (int i = 0; i < 32; ++i) sc[qloc][s + 32 * i] *= inv;
        __syncthreads();

        // ---- write attn rows (coalesced float4), layout [B, Lq, H, Lk] ----
        #pragma unroll
        for (int rr = 0; rr < 8; ++rr) {
            float4 v = ((const float4*)&sc[rr][0])[t];
            *(float4*)&attn[((((size_t)b * NL) + q0 + rr) * NH + h) * NL + t * 4] = v;
        }

        // ---- PV: 16 chunks of 64 m-rows staged in LDS ----
        for (int ch = 0; ch < 16; ++ch) {
            __syncthreads();
            #pragma unroll
            for (int i = 0; i < 4; ++i) {
                int idx = t + 256 * i;
                int vrow = idx >> 4;
                int vc = (idx & 15) * 4;
                *(float4*)&vt[vrow][vc] =
                    *(const float4*)&v_proj[((size_t)b * NL + ch * 64 + vrow) * NDK + vc];
            }
            __syncthreads();
            #pragma unroll
            for (int mm = 0; mm < 64; ++mm) {
                float p = sc[qloc][ch * 64 + mm];
                float2 v2 = *(const float2*)&vt[mm][c0];
                accx += p * v2.x;
                accy += p * v2.y;
            }
        }
    }

    float2 o;
    o.x = accx * (1.f / 16.f);
    o.y = accy * (1.f / 16.f);
    *(float2*)&head_mean[((size_t)b * NL + q0 + qloc) * NDK + c0] = o;
}

// ---------------------------------------------------------------------------
// Stage 3: output[r, :] = head_mean[r, :] @ wo + bo.   [4096 x 64] @ [64 x 1024]
// block 256, grid 512 (8 rows per wg). Thread owns 4 cols x 8 rows.
// ---------------------------------------------------------------------------
__global__ __launch_bounds__(256) void out_proj_kernel(
    const float* __restrict__ head_mean, const float* __restrict__ wo,
    const float* __restrict__ bo, float* __restrict__ out)
{
    const int t = threadIdx.x;
    const int row0 = blockIdx.x * 8;
    __shared__ float hm[8][64];
    if (t < 128) {
        int r = t >> 4;
        int c = (t & 15) * 4;
        *(float4*)&hm[r][c] = *(const float4*)&head_mean[((size_t)row0 + r) * NDK + c];
    }
    __syncthreads();

    float acc[8][4];
    #pragma unroll
    for (int r = 0; r < 8; ++r)
        #pragma unroll
        for (int j = 0; j < 4; ++j) acc[r][j] = 0.f;

    for (int k = 0; k < 64; ++k) {
        float w0 = wo[(size_t)k * ND + t];
        float w1 = wo[(size_t)k * ND + t + 256];
        float w2 = wo[(size_t)k * ND + t + 512];
        float w3 = wo[(size_t)k * ND + t + 768];
        #pragma unroll
        for (int r = 0; r < 8; ++r) {
            float hv = hm[r][k];
            acc[r][0] += hv * w0;
            acc[r][1] += hv * w1;
            acc[r][2] += hv * w2;
            acc[r][3] += hv * w3;
        }
    }
    #pragma unroll
    for (int r = 0; r < 8; ++r) {
        out[((size_t)row0 + r) * ND + t      ] = acc[r][0] + bo[t];
        out[((size_t)row0 + r) * ND + t + 256] = acc[r][1] + bo[t + 256];
        out[((size_t)row0 + r) * ND + t + 512] = acc[r][2] + bo[t + 512];
        out[((size_t)row0 + r) * ND + t + 768] = acc[r][3] + bo[t + 768];
    }
}

// ---------------------------------------------------------------------------
extern "C" void kernel_launch(void* const* d_in, const int* in_sizes, int n_in,
                              void* d_out, int out_size, void* d_ws, size_t ws_size,
                              hipStream_t stream) {
    const float* query  = (const float*)d_in[0];
    const float* key_in = (const float*)d_in[1];
    const float* value  = (const float*)d_in[2];
    const float* wq     = (const float*)d_in[3];
    const float* bq     = (const float*)d_in[4];
    const float* wk     = (const float*)d_in[5];
    const float* bk     = (const float*)d_in[6];
    const float* wv     = (const float*)d_in[7];
    const float* bv     = (const float*)d_in[8];
    const float* wo     = (const float*)d_in[9];
    const float* bo     = (const float*)d_in[10];

    float* out  = (float*)d_out;                       // [B, L, D]
    float* attn = out + (size_t)NB * NL * ND;          // [B, L, H, L]

    float* ws        = (float*)d_ws;
    float* q_all     = ws;                                      // B*H*L*DK
    float* k_all     = q_all + (size_t)NB * NH * NL * NDK;      // B*H*L*DK
    float* v_proj    = k_all + (size_t)NB * NH * NL * NDK;      // B*L*DK
    float* head_mean = v_proj + (size_t)NB * NL * NDK;          // B*L*DK

    proj_kernel<<<dim3(64, 33), 256, 0, stream>>>(
        query, key_in, value, wq, bq, wk, bk, wv, bv, q_all, k_all, v_proj);
    attn_kernel<<<dim3(NL / 8, NB), 256, 0, stream>>>(
        q_all, k_all, v_proj, attn, head_mean);
    out_proj_kernel<<<dim3(NB * NL / 8), 256, 0, stream>>>(
        head_mean, wo, bo, out);
}

// Round 2
// 968.468 us; speedup vs baseline: 1.9515x; 1.9515x over previous
//
#include <hip/hip_runtime.h>
#include <math.h>

// Problem constants (B=4, L=1024, D=1024, H=16, DK=64)
#define NB 4
#define NL 1024
#define ND 1024
#define NH 16
#define NDK 64

typedef __attribute__((ext_vector_type(8))) short short8;
typedef __attribute__((ext_vector_type(4))) float f32x4;

__device__ inline ushort f2bf(float f) {
    uint x = __float_as_uint(f);
    x += 0x7FFFu + ((x >> 16) & 1u);   // RNE
    return (ushort)(x >> 16);
}
__device__ inline float bf2f(ushort u) { return __uint_as_float(((uint)u) << 16); }

// ---------------------------------------------------------------------------
// Stage 1: projections (fp32 compute, bf16 stores).
// q_all[b,h,l,k] = 0.125*(query@wq + bq)   (z = 0..15)   [scale folded in]
// k_all[b,h,l,k] = key@wk + bk             (z = 16..31)
// v_proj[b,l,k]  = value@wv + bv           (z = 32)
// ---------------------------------------------------------------------------
__global__ __launch_bounds__(256) void proj_kernel(
    const float* __restrict__ query, const float* __restrict__ key_in,
    const float* __restrict__ value,
    const float* __restrict__ wq, const float* __restrict__ bq,
    const float* __restrict__ wk, const float* __restrict__ bk,
    const float* __restrict__ wv, const float* __restrict__ bv,
    ushort* __restrict__ q_all, ushort* __restrict__ k_all,
    ushort* __restrict__ v_proj)
{
    const int t = threadIdx.x;
    const int row0 = blockIdx.x * 64;
    const int z = blockIdx.y;

    const float* A; const float* W; const float* bias; ushort* C;
    int h, nh; float oscale;
    if (z < 16)      { A = query;  W = wq + (size_t)z*ND*NDK;      bias = bq + z*NDK;      C = q_all;  h = z;    nh = 16; oscale = 0.125f; }
    else if (z < 32) { A = key_in; W = wk + (size_t)(z-16)*ND*NDK; bias = bk + (z-16)*NDK; C = k_all;  h = z-16; nh = 16; oscale = 1.0f; }
    else             { A = value;  W = wv;                         bias = bv;              C = v_proj; h = 0;    nh = 1;  oscale = 1.0f; }

    __shared__ float At[64][84];
    __shared__ float Wt[64][64];

    const int r0 = (t >> 4) * 4;
    const int c0 = (t & 15) * 4;

    float acc[4][4];
    #pragma unroll
    for (int i = 0; i < 4; ++i)
        #pragma unroll
        for (int j = 0; j < 4; ++j) acc[i][j] = 0.f;

    for (int kt = 0; kt < 16; ++kt) {
        const int k0 = kt * 64;
        __syncthreads();
        #pragma unroll
        for (int i = 0; i < 4; ++i) {
            int idx = t + 256 * i;
            int ar = idx >> 4;
            int kc = (idx & 15) * 4;
            float4 v = *(const float4*)&A[(size_t)(row0 + ar) * ND + k0 + kc];
            *(float4*)&At[ar][kc] = v;
        }
        #pragma unroll
        for (int i = 0; i < 4; ++i) {
            int idx = t + 256 * i;
            int wr = idx >> 4;
            int wc = (idx & 15) * 4;
            float4 v = *(const float4*)&W[(size_t)(k0 + wr) * NDK + wc];
            *(float4*)&Wt[wr][wc] = v;
        }
        __syncthreads();
        #pragma unroll
        for (int kk = 0; kk < 64; kk += 4) {
            float4 a[4], w[4];
            #pragma unroll
            for (int i = 0; i < 4; ++i) a[i] = *(const float4*)&At[r0 + i][kk];
            #pragma unroll
            for (int q = 0; q < 4; ++q) w[q] = *(const float4*)&Wt[kk + q][c0];
            #pragma unroll
            for (int i = 0; i < 4; ++i) {
                #pragma unroll
                for (int j = 0; j < 4; ++j) {
                    acc[i][j] += a[i].x * ((const float*)&w[0])[j]
                               + a[i].y * ((const float*)&w[1])[j]
                               + a[i].z * ((const float*)&w[2])[j]
                               + a[i].w * ((const float*)&w[3])[j];
                }
            }
        }
    }

    float4 bias4 = *(const float4*)&bias[c0];
    #pragma unroll
    for (int i = 0; i < 4; ++i) {
        int r = row0 + r0 + i;
        int bb = r >> 10;
        int l  = r & 1023;
        float ox = (acc[i][0] + bias4.x) * oscale;
        float oy = (acc[i][1] + bias4.y) * oscale;
        float oz = (acc[i][2] + bias4.z) * oscale;
        float ow = (acc[i][3] + bias4.w) * oscale;
        uint u0 = (uint)f2bf(ox) | ((uint)f2bf(oy) << 16);
        uint u1 = (uint)f2bf(oz) | ((uint)f2bf(ow) << 16);
        *(uint2*)(C + (((size_t)bb * nh + h) * NL + l) * NDK + c0) = make_uint2(u0, u1);
    }
}

// ---------------------------------------------------------------------------
// V transpose: vT[b][v][l] = v_proj[b][l][v]  (bf16), tiles of 64 l-rows.
// ---------------------------------------------------------------------------
__global__ __launch_bounds__(256) void vtrans_kernel(
    const ushort* __restrict__ vp, ushort* __restrict__ vT)
{
    __shared__ ushort tl[64][72];
    const int t = threadIdx.x;
    const int l0 = blockIdx.x * 64;
    const int b = blockIdx.y;

    int row = t >> 2, c0 = (t & 3) * 16;
    const ushort* src = vp + ((size_t)b * NL + l0 + row) * NDK + c0;
    #pragma unroll
    for (int j4 = 0; j4 < 4; ++j4) {
        uint2 d = *(const uint2*)(src + j4 * 4);
        tl[c0 + j4*4 + 0][row] = (ushort)(d.x & 0xFFFF);
        tl[c0 + j4*4 + 1][row] = (ushort)(d.x >> 16);
        tl[c0 + j4*4 + 2][row] = (ushort)(d.y & 0xFFFF);
        tl[c0 + j4*4 + 3][row] = (ushort)(d.y >> 16);
    }
    __syncthreads();
    int v = t >> 2, lc = (t & 3) * 16;
    ushort* dst = vT + ((size_t)b * NDK + v) * NL + l0 + lc;
    #pragma unroll
    for (int j4 = 0; j4 < 4; ++j4) {
        uint u0 = (uint)tl[v][lc + j4*4 + 0] | ((uint)tl[v][lc + j4*4 + 1] << 16);
        uint u1 = (uint)tl[v][lc + j4*4 + 2] | ((uint)tl[v][lc + j4*4 + 3] << 16);
        *(uint2*)(dst + j4 * 4) = make_uint2(u0, u1);
    }
}

// ---------------------------------------------------------------------------
// Stage 2: MFMA attention. One block per (b, h, 32-q-row tile). 4 waves.
// Wave w: q sub-tile qh=w&1 (16 rows), k half kh=w>>1 (512 cols).
// QK^T swapped (D col = q) -> row stats reduce with 2 shfl_xor.
// Scores staged bf16 in LDS [32][1024], XOR-swizzled (row&7)<<4.
// ---------------------------------------------------------------------------
__global__ __launch_bounds__(256) void attn_mfma_kernel(
    const ushort* __restrict__ q_all, const ushort* __restrict__ k_all,
    const ushort* __restrict__ vT,
    float* __restrict__ attn, float* __restrict__ heads)
{
    __shared__ char raw[65536 + 640];
    float* mx   = (float*)(raw + 65536);         // [2][32]
    float* smv  = (float*)(raw + 65536 + 256);   // [2][32]
    float* invb = (float*)(raw + 65536 + 512);   // [32]

    const int t = threadIdx.x;
    const int w = t >> 6, l = t & 63;
    const int hi = l >> 4, lo = l & 15;
    const int qh = w & 1, kh = w >> 1;
    const int q0 = blockIdx.x * 32;
    const int h  = blockIdx.y;
    const int b  = blockIdx.z;
    const size_t bh = ((size_t)b * NH + h) * NL;

    const int qr = qh * 16 + lo;              // score row owned by this lane's D-col
    const uint swz = ((uint)(qr & 7)) << 4;

    // persistent Q fragments (B operand: col=q, elems=d)
    short8 Qb0 = *(const short8*)(q_all + (bh + q0 + qr) * NDK + hi * 8);
    short8 Qb1 = *(const short8*)(q_all + (bh + q0 + qr) * NDK + 32 + hi * 8);

    // ---- QK^T: raw scores -> LDS (bf16), online per-lane max ----
    float mmax = -3.0e38f;
    for (int kt = 0; kt < 32; ++kt) {
        const int kbase = kh * 512 + kt * 16;
        short8 Ka0 = *(const short8*)(k_all + (bh + kbase + lo) * NDK + hi * 8);
        short8 Ka1 = *(const short8*)(k_all + (bh + kbase + lo) * NDK + 32 + hi * 8);
        f32x4 s = {0.f, 0.f, 0.f, 0.f};
        s = __builtin_amdgcn_mfma_f32_16x16x32_bf16(Ka0, Qb0, s, 0, 0, 0);
        s = __builtin_amdgcn_mfma_f32_16x16x32_bf16(Ka1, Qb1, s, 0, 0, 0);
        mmax = fmaxf(mmax, fmaxf(fmaxf(s[0], s[1]), fmaxf(s[2], s[3])));
        uint u0 = (uint)f2bf(s[0]) | ((uint)f2bf(s[1]) << 16);
        uint u1 = (uint)f2bf(s[2]) | ((uint)f2bf(s[3]) << 16);
        uint byteoff = (uint)qr * 2048u + ((((uint)(kbase + hi * 4)) * 2u) ^ swz);
        *(uint2*)(raw + byteoff) = make_uint2(u0, u1);
    }
    mmax = fmaxf(mmax, __shfl_xor(mmax, 16));
    mmax = fmaxf(mmax, __shfl_xor(mmax, 32));
    if (l < 16) mx[kh * 32 + qh * 16 + l] = mmax;
    __syncthreads();
    const float mf = fmaxf(mx[qr], mx[32 + qr]);

    // ---- exp pass: s -> e = exp(s - m), accumulate sum, store back ----
    float ssum = 0.f;
    for (int kt = 0; kt < 32; ++kt) {
        const int kbase = kh * 512 + kt * 16;
        uint byteoff = (uint)qr * 2048u + ((((uint)(kbase + hi * 4)) * 2u) ^ swz);
        uint2 v = *(uint2*)(raw + byteoff);
        float e0 = __expf(bf2f((ushort)(v.x & 0xFFFF)) - mf);
        float e1 = __expf(bf2f((ushort)(v.x >> 16)) - mf);
        float e2 = __expf(bf2f((ushort)(v.y & 0xFFFF)) - mf);
        float e3 = __expf(bf2f((ushort)(v.y >> 16)) - mf);
        ssum += (e0 + e1) + (e2 + e3);
        uint u0 = (uint)f2bf(e0) | ((uint)f2bf(e1) << 16);
        uint u1 = (uint)f2bf(e2) | ((uint)f2bf(e3) << 16);
        *(uint2*)(raw + byteoff) = make_uint2(u0, u1);
    }
    ssum += __shfl_xor(ssum, 16);
    ssum += __shfl_xor(ssum, 32);
    if (l < 16) smv[kh * 32 + qh * 16 + l] = ssum;
    __syncthreads();
    if (t < 32) invb[t] = 1.0f / (smv[t] + smv[32 + t]);
    __syncthreads();

    // ---- write normalized attn rows: [B, Lq, H, Lk], float4 coalesced ----
    for (int rr = 0; rr < 32; ++rr) {
        uint byteoff = (uint)rr * 2048u + (((uint)t * 8u) ^ (((uint)(rr & 7)) << 4));
        uint2 v = *(uint2*)(raw + byteoff);
        float inv = invb[rr];
        float4 o;
        o.x = bf2f((ushort)(v.x & 0xFFFF)) * inv;
        o.y = bf2f((ushort)(v.x >> 16)) * inv;
        o.z = bf2f((ushort)(v.y & 0xFFFF)) * inv;
        o.w = bf2f((ushort)(v.y >> 16)) * inv;
        *(float4*)(attn + (((size_t)b * NL + q0 + rr) * NH + h) * NL + (size_t)t * 4) = o;
    }

    // ---- PV: D[q][v] = sum_k e[q][k] * V[k][v], per-wave k-half partials ----
    f32x4 acc0 = {0.f,0.f,0.f,0.f}, acc1 = {0.f,0.f,0.f,0.f};
    f32x4 acc2 = {0.f,0.f,0.f,0.f}, acc3 = {0.f,0.f,0.f,0.f};
    for (int kc = 0; kc < 16; ++kc) {
        const int kchunk = kh * 512 + kc * 32;
        short8 pa = *(short8*)(raw + (uint)qr * 2048u + ((((uint)(kchunk + hi * 8)) * 2u) ^ swz));
        short8 b0 = *(const short8*)(vT + ((size_t)(b * NDK +  0 + lo)) * NL + kchunk + hi * 8);
        short8 b1 = *(const short8*)(vT + ((size_t)(b * NDK + 16 + lo)) * NL + kchunk + hi * 8);
        short8 b2 = *(const short8*)(vT + ((size_t)(b * NDK + 32 + lo)) * NL + kchunk + hi * 8);
        short8 b3 = *(const short8*)(vT + ((size_t)(b * NDK + 48 + lo)) * NL + kchunk + hi * 8);
        acc0 = __builtin_amdgcn_mfma_f32_16x16x32_bf16(pa, b0, acc0, 0, 0, 0);
        acc1 = __builtin_amdgcn_mfma_f32_16x16x32_bf16(pa, b1, acc1, 0, 0, 0);
        acc2 = __builtin_amdgcn_mfma_f32_16x16x32_bf16(pa, b2, acc2, 0, 0, 0);
        acc3 = __builtin_amdgcn_mfma_f32_16x16x32_bf16(pa, b3, acc3, 0, 0, 0);
    }
    __syncthreads();   // all waves done READING sc before aliasing writes
    float* pvp = (float*)raw;   // [2 kh][32 q][64 v] f32 = 16KB, aliases sc
    #pragma unroll
    for (int r = 0; r < 4; ++r) {
        int qq = qh * 16 + hi * 4 + r;
        pvp[(kh * 32 + qq) * 64 +  0 + lo] = acc0[r];
        pvp[(kh * 32 + qq) * 64 + 16 + lo] = acc1[r];
        pvp[(kh * 32 + qq) * 64 + 32 + lo] = acc2[r];
        pvp[(kh * 32 + qq) * 64 + 48 + lo] = acc3[r];
    }
    __syncthreads();
    #pragma unroll
    for (int i = 0; i < 8; ++i) {
        int idx = t + 256 * i;              // 0..2047 = q*64 + v
        int qq = idx >> 6, vv = idx & 63;
        float s2 = pvp[idx] + pvp[idx + 2048];
        heads[(bh + q0 + qq) * NDK + vv] = s2 * invb[qq];
    }
}

// ---------------------------------------------------------------------------
// head mean over H
// ---------------------------------------------------------------------------
__global__ __launch_bounds__(256) void mean_kernel(
    const float* __restrict__ heads, float* __restrict__ hm)
{
    int id = blockIdx.x * 256 + threadIdx.x;     // 65536 float4 groups
    int b = id >> 14;
    int r = id & 16383;                          // l*16 + v4
    const float4* src = (const float4*)heads;
    float sx = 0.f, sy = 0.f, sz = 0.f, sw = 0.f;
    #pragma unroll
    for (int h2 = 0; h2 < 16; ++h2) {
        float4 v = src[(((size_t)b * 16 + h2) << 14) + r];
        sx += v.x; sy += v.y; sz += v.z; sw += v.w;
    }
    float4 o; o.x = sx * 0.0625f; o.y = sy * 0.0625f; o.z = sz * 0.0625f; o.w = sw * 0.0625f;
    ((float4*)hm)[(((size_t)b) << 14) + r] = o;
}

// ---------------------------------------------------------------------------
// Stage 3: output projection (unchanged, f32)
// ---------------------------------------------------------------------------
__global__ __launch_bounds__(256) void out_proj_kernel(
    const float* __restrict__ head_mean, const float* __restrict__ wo,
    const float* __restrict__ bo, float* __restrict__ out)
{
    const int t = threadIdx.x;
    const int row0 = blockIdx.x * 8;
    __shared__ float hm[8][64];
    if (t < 128) {
        int r = t >> 4;
        int c = (t & 15) * 4;
        *(float4*)&hm[r][c] = *(const float4*)&head_mean[((size_t)row0 + r) * NDK + c];
    }
    __syncthreads();

    float acc[8][4];
    #pragma unroll
    for (int r = 0; r < 8; ++r)
        #pragma unroll
        for (int j = 0; j < 4; ++j) acc[r][j] = 0.f;

    for (int k = 0; k < 64; ++k) {
        float w0 = wo[(size_t)k * ND + t];
        float w1 = wo[(size_t)k * ND + t + 256];
        float w2 = wo[(size_t)k * ND + t + 512];
        float w3 = wo[(size_t)k * ND + t + 768];
        #pragma unroll
        for (int r = 0; r < 8; ++r) {
            float hv = hm[r][k];
            acc[r][0] += hv * w0;
            acc[r][1] += hv * w1;
            acc[r][2] += hv * w2;
            acc[r][3] += hv * w3;
        }
    }
    #pragma unroll
    for (int r = 0; r < 8; ++r) {
        out[((size_t)row0 + r) * ND + t      ] = acc[r][0] + bo[t];
        out[((size_t)row0 + r) * ND + t + 256] = acc[r][1] + bo[t + 256];
        out[((size_t)row0 + r) * ND + t + 512] = acc[r][2] + bo[t + 512];
        out[((size_t)row0 + r) * ND + t + 768] = acc[r][3] + bo[t + 768];
    }
}

// ---------------------------------------------------------------------------
extern "C" void kernel_launch(void* const* d_in, const int* in_sizes, int n_in,
                              void* d_out, int out_size, void* d_ws, size_t ws_size,
                              hipStream_t stream) {
    const float* query  = (const float*)d_in[0];
    const float* key_in = (const float*)d_in[1];
    const float* value  = (const float*)d_in[2];
    const float* wq     = (const float*)d_in[3];
    const float* bq     = (const float*)d_in[4];
    const float* wk     = (const float*)d_in[5];
    const float* bk     = (const float*)d_in[6];
    const float* wv     = (const float*)d_in[7];
    const float* bv     = (const float*)d_in[8];
    const float* wo     = (const float*)d_in[9];
    const float* bo     = (const float*)d_in[10];

    float* out  = (float*)d_out;                       // [B, L, D]
    float* attn = out + (size_t)NB * NL * ND;          // [B, L, H, L]

    ushort* q_all  = (ushort*)d_ws;                               // B*H*L*DK bf16
    ushort* k_all  = q_all + (size_t)NB * NH * NL * NDK;          // B*H*L*DK bf16
    ushort* v_proj = k_all + (size_t)NB * NH * NL * NDK;          // B*L*DK bf16
    ushort* vT     = v_proj + (size_t)NB * NL * NDK;              // B*DK*L bf16
    float*  heads  = (float*)(vT + (size_t)NB * NL * NDK);        // B*H*L*DK f32
    float*  head_mean = heads + (size_t)NB * NH * NL * NDK;       // B*L*DK f32

    proj_kernel<<<dim3(64, 33), 256, 0, stream>>>(
        query, key_in, value, wq, bq, wk, bk, wv, bv, q_all, k_all, v_proj);
    vtrans_kernel<<<dim3(16, NB), 256, 0, stream>>>(v_proj, vT);
    attn_mfma_kernel<<<dim3(32, NH, NB), 256, 0, stream>>>(
        q_all, k_all, vT, attn, heads);
    mean_kernel<<<dim3(256), 256, 0, stream>>>(heads, head_mean);
    out_proj_kernel<<<dim3(NB * NL / 8), 256, 0, stream>>>(
        head_mean, wo, bo, out);
}

// Round 3
// 259.148 us; speedup vs baseline: 7.2930x; 3.7371x over previous
//
#include <hip/hip_runtime.h>
#include <math.h>

// Problem constants (B=4, L=1024, D=1024, H=16, DK=64)
#define NB 4
#define NL 1024
#define ND 1024
#define NH 16
#define NDK 64

typedef __attribute__((ext_vector_type(8))) short short8;
typedef __attribute__((ext_vector_type(4))) float f32x4;

__device__ inline ushort f2bf(float f) {
    uint x = __float_as_uint(f);
    x += 0x7FFFu + ((x >> 16) & 1u);   // RNE
    return (ushort)(x >> 16);
}
__device__ inline float bf2f(ushort u) { return __uint_as_float(((uint)u) << 16); }

// ---------------------------------------------------------------------------
// Weight cvt+transpose: wqT[h*64+dk][d] = bf16(wq[h][d][dk])  (B^T layout)
// grid (16 d-tiles, 33): y<16 wq head y; y<32 wk head y-16; y==32 wv (+zero pad
// rows 64..127 of wvT so the GEMM can stage a full 128-row B tile).
// ---------------------------------------------------------------------------
__global__ __launch_bounds__(256) void cvtw_kernel(
    const float* __restrict__ wq, const float* __restrict__ wk,
    const float* __restrict__ wv,
    ushort* __restrict__ wqT, ushort* __restrict__ wkT, ushort* __restrict__ wvT)
{
    __shared__ ushort tl[64][72];
    const int t = threadIdx.x;
    const int d0 = blockIdx.x * 64;
    const int y = blockIdx.y;
    const float* src; ushort* dst; int h;
    if (y < 16)      { src = wq + (size_t)y * ND * NDK;        dst = wqT; h = y; }
    else if (y < 32) { src = wk + (size_t)(y - 16) * ND * NDK; dst = wkT; h = y - 16; }
    else             { src = wv;                               dst = wvT; h = 0; }

    int r = t >> 2, c0 = (t & 3) * 16;
    const float* s = src + (size_t)(d0 + r) * NDK + c0;
    #pragma unroll
    for (int j = 0; j < 16; j += 4) {
        float4 v = *(const float4*)(s + j);
        tl[c0 + j + 0][r] = f2bf(v.x);
        tl[c0 + j + 1][r] = f2bf(v.y);
        tl[c0 + j + 2][r] = f2bf(v.z);
        tl[c0 + j + 3][r] = f2bf(v.w);
    }
    __syncthreads();
    int vv = t >> 2, lc = (t & 3) * 16;
    ushort* d = dst + ((size_t)h * 64 + vv) * ND + d0 + lc;
    #pragma unroll
    for (int j = 0; j < 16; j += 8) {
        short8 o;
        #pragma unroll
        for (int e = 0; e < 8; ++e) o[e] = (short)tl[vv][lc + j + e];
        *(short8*)(d + j) = o;
    }
    if (y == 32) {
        ushort* zp = wvT + ((size_t)(64 + (t >> 2))) * ND + d0 + (t & 3) * 16;
        short8 z8 = {0,0,0,0,0,0,0,0};
        *(short8*)(zp) = z8;
        *(short8*)(zp + 8) = z8;
    }
}

// ---------------------------------------------------------------------------
// MFMA projection GEMM. 128x128 tile, BK=64, 256 thr (4 waves 2x2 of 64x64).
// A = fp32 input rows (cvt->bf16 during reg-staging); B = bf16 [N][K] weights.
// LDS tiles XOR-swizzled (byte ^= (row&7)<<4) for conflict-free ds_read_b128.
// z=0: Q (scale 0.125, out q_all[b,h,l,dk]); z=1: K; z=2: V (N=64).
// Grid 544 = 8*68, XCD-chunked swizzle; nt fastest so same-XCD blocks share A.
// ---------------------------------------------------------------------------
__global__ __launch_bounds__(256) void proj_gemm(
    const float* __restrict__ query, const float* __restrict__ key_in,
    const float* __restrict__ value,
    const ushort* __restrict__ wqT, const ushort* __restrict__ wkT,
    const ushort* __restrict__ wvT,
    const float* __restrict__ bq, const float* __restrict__ bk,
    const float* __restrict__ bv,
    ushort* __restrict__ q_all, ushort* __restrict__ k_all,
    ushort* __restrict__ v_proj)
{
    __shared__ char lds[32768];   // A bf16 [128][64] @0 ; B bf16 [128][64] @16384

    int id = blockIdx.x;
    int wg = (id & 7) * 68 + (id >> 3);   // 544 = 8 XCDs x 68, bijective
    int z, mt, nt;
    if (wg < 512) { z = wg >> 8; int rem = wg & 255; mt = rem >> 3; nt = rem & 7; }
    else          { z = 2; mt = wg - 512; nt = 0; }

    const float* A; const ushort* Bw; const float* bias; ushort* C; float scale;
    if (z == 0)      { A = query;  Bw = wqT; bias = bq; C = q_all;  scale = 0.125f; }
    else if (z == 1) { A = key_in; Bw = wkT; bias = bk; C = k_all;  scale = 1.0f; }
    else             { A = value;  Bw = wvT; bias = bv; C = v_proj; scale = 1.0f; }

    const int t = threadIdx.x;
    const int w = t >> 6, l = t & 63;
    const int lo16 = l & 15, hi = l >> 4;
    const int wm = w >> 1, wn = w & 1;
    const int m0 = mt * 128, n0 = nt * 128;

    f32x4 acc[4][4];
    #pragma unroll
    for (int mi = 0; mi < 4; ++mi)
        #pragma unroll
        for (int ni = 0; ni < 4; ++ni) acc[mi][ni] = (f32x4){0.f, 0.f, 0.f, 0.f};

    const int a_r = t >> 4, a_f4 = t & 15;   // A: rows a_r+16i, float4-col a_f4
    const int b_r = t >> 3, b_k8 = t & 7;    // B: rows b_r+32i, short8-col b_k8

    for (int kt = 0; kt < 16; ++kt) {
        const int k0 = kt * 64;
        __syncthreads();
        #pragma unroll
        for (int i = 0; i < 8; ++i) {
            int row = a_r + 16 * i;
            float4 v = *(const float4*)(A + (size_t)(m0 + row) * ND + k0 + a_f4 * 4);
            uint u0 = (uint)f2bf(v.x) | ((uint)f2bf(v.y) << 16);
            uint u1 = (uint)f2bf(v.z) | ((uint)f2bf(v.w) << 16);
            uint off = ((uint)row * 128u + (uint)a_f4 * 8u) ^ (((uint)(row & 7)) << 4);
            *(uint2*)(lds + off) = make_uint2(u0, u1);
        }
        #pragma unroll
        for (int i = 0; i < 4; ++i) {
            int row = b_r + 32 * i;
            short8 v = *(const short8*)(Bw + (size_t)(n0 + row) * ND + k0 + b_k8 * 8);
            uint off = ((uint)row * 128u + (uint)b_k8 * 16u) ^ (((uint)(row & 7)) << 4);
            *(short8*)(lds + 16384 + off) = v;
        }
        __syncthreads();
        #pragma unroll
        for (int ks = 0; ks < 2; ++ks) {
            short8 Af[4], Bf[4];
            #pragma unroll
            for (int mi = 0; mi < 4; ++mi) {
                int row = wm * 64 + mi * 16 + lo16;
                uint off = ((uint)row * 128u + (uint)(ks * 64 + hi * 16)) ^ (((uint)(row & 7)) << 4);
                Af[mi] = *(short8*)(lds + off);
            }
            #pragma unroll
            for (int ni = 0; ni < 4; ++ni) {
                int row = wn * 64 + ni * 16 + lo16;
                uint off = ((uint)row * 128u + (uint)(ks * 64 + hi * 16)) ^ (((uint)(row & 7)) << 4);
                Bf[ni] = *(short8*)(lds + 16384 + off);
            }
            #pragma unroll
            for (int mi = 0; mi < 4; ++mi)
                #pragma unroll
                for (int ni = 0; ni < 4; ++ni)
                    acc[mi][ni] = __builtin_amdgcn_mfma_f32_16x16x32_bf16(
                        Af[mi], Bf[ni], acc[mi][ni], 0, 0, 0);
        }
    }

    // epilogue: bias + scale, bf16 store. D frag: row=(l>>4)*4+r, col=l&15.
    const int m0w = m0 + wm * 64, n0w = n0 + wn * 64;
    #pragma unroll
    for (int ni = 0; ni < 4; ++ni) {
        int n = n0w + ni * 16 + lo16;
        float bs = (z == 2 && n >= 64) ? 0.f : bias[n];
        #pragma unroll
        for (int mi = 0; mi < 4; ++mi) {
            #pragma unroll
            for (int r = 0; r < 4; ++r) {
                int m = m0w + mi * 16 + hi * 4 + r;
                ushort o = f2bf((acc[mi][ni][r] + bs) * scale);
                if (z < 2) {
                    size_t addr = ((((size_t)(m >> 10)) * NH + (n >> 6)) * NL + (m & 1023)) * NDK + (n & 63);
                    C[addr] = o;
                } else if (n < 64) {
                    C[(size_t)m * NDK + n] = o;
                }
            }
        }
    }
}

// ---------------------------------------------------------------------------
// V transpose: vT[b][v][l] = v_proj[b][l][v]  (bf16), tiles of 64 l-rows.
// ---------------------------------------------------------------------------
__global__ __launch_bounds__(256) void vtrans_kernel(
    const ushort* __restrict__ vp, ushort* __restrict__ vT)
{
    __shared__ ushort tl[64][72];
    const int t = threadIdx.x;
    const int l0 = blockIdx.x * 64;
    const int b = blockIdx.y;

    int row = t >> 2, c0 = (t & 3) * 16;
    const ushort* src = vp + ((size_t)b * NL + l0 + row) * NDK + c0;
    #pragma unroll
    for (int j4 = 0; j4 < 4; ++j4) {
        uint2 d = *(const uint2*)(src + j4 * 4);
        tl[c0 + j4*4 + 0][row] = (ushort)(d.x & 0xFFFF);
        tl[c0 + j4*4 + 1][row] = (ushort)(d.x >> 16);
        tl[c0 + j4*4 + 2][row] = (ushort)(d.y & 0xFFFF);
        tl[c0 + j4*4 + 3][row] = (ushort)(d.y >> 16);
    }
    __syncthreads();
    int v = t >> 2, lc = (t & 3) * 16;
    ushort* dst = vT + ((size_t)b * NDK + v) * NL + l0 + lc;
    #pragma unroll
    for (int j4 = 0; j4 < 4; ++j4) {
        uint u0 = (uint)tl[v][lc + j4*4 + 0] | ((uint)tl[v][lc + j4*4 + 1] << 16);
        uint u1 = (uint)tl[v][lc + j4*4 + 2] | ((uint)tl[v][lc + j4*4 + 3] << 16);
        *(uint2*)(dst + j4 * 4) = make_uint2(u0, u1);
    }
}

// ---------------------------------------------------------------------------
// Stage 2: MFMA attention (unchanged from round 2 — verified).
// ---------------------------------------------------------------------------
__global__ __launch_bounds__(256) void attn_mfma_kernel(
    const ushort* __restrict__ q_all, const ushort* __restrict__ k_all,
    const ushort* __restrict__ vT,
    float* __restrict__ attn, float* __restrict__ heads)
{
    __shared__ char raw[65536 + 640];
    float* mx   = (float*)(raw + 65536);
    float* smv  = (float*)(raw + 65536 + 256);
    float* invb = (float*)(raw + 65536 + 512);

    const int t = threadIdx.x;
    const int w = t >> 6, l = t & 63;
    const int hi = l >> 4, lo = l & 15;
    const int qh = w & 1, kh = w >> 1;
    const int q0 = blockIdx.x * 32;
    const int h  = blockIdx.y;
    const int b  = blockIdx.z;
    const size_t bh = ((size_t)b * NH + h) * NL;

    const int qr = qh * 16 + lo;
    const uint swz = ((uint)(qr & 7)) << 4;

    short8 Qb0 = *(const short8*)(q_all + (bh + q0 + qr) * NDK + hi * 8);
    short8 Qb1 = *(const short8*)(q_all + (bh + q0 + qr) * NDK + 32 + hi * 8);

    float mmax = -3.0e38f;
    for (int kt = 0; kt < 32; ++kt) {
        const int kbase = kh * 512 + kt * 16;
        short8 Ka0 = *(const short8*)(k_all + (bh + kbase + lo) * NDK + hi * 8);
        short8 Ka1 = *(const short8*)(k_all + (bh + kbase + lo) * NDK + 32 + hi * 8);
        f32x4 s = {0.f, 0.f, 0.f, 0.f};
        s = __builtin_amdgcn_mfma_f32_16x16x32_bf16(Ka0, Qb0, s, 0, 0, 0);
        s = __builtin_amdgcn_mfma_f32_16x16x32_bf16(Ka1, Qb1, s, 0, 0, 0);
        mmax = fmaxf(mmax, fmaxf(fmaxf(s[0], s[1]), fmaxf(s[2], s[3])));
        uint u0 = (uint)f2bf(s[0]) | ((uint)f2bf(s[1]) << 16);
        uint u1 = (uint)f2bf(s[2]) | ((uint)f2bf(s[3]) << 16);
        uint byteoff = (uint)qr * 2048u + ((((uint)(kbase + hi * 4)) * 2u) ^ swz);
        *(uint2*)(raw + byteoff) = make_uint2(u0, u1);
    }
    mmax = fmaxf(mmax, __shfl_xor(mmax, 16));
    mmax = fmaxf(mmax, __shfl_xor(mmax, 32));
    if (l < 16) mx[kh * 32 + qh * 16 + l] = mmax;
    __syncthreads();
    const float mf = fmaxf(mx[qr], mx[32 + qr]);

    float ssum = 0.f;
    for (int kt = 0; kt < 32; ++kt) {
        const int kbase = kh * 512 + kt * 16;
        uint byteoff = (uint)qr * 2048u + ((((uint)(kbase + hi * 4)) * 2u) ^ swz);
        uint2 v = *(uint2*)(raw + byteoff);
        float e0 = __expf(bf2f((ushort)(v.x & 0xFFFF)) - mf);
        float e1 = __expf(bf2f((ushort)(v.x >> 16)) - mf);
        float e2 = __expf(bf2f((ushort)(v.y & 0xFFFF)) - mf);
        float e3 = __expf(bf2f((ushort)(v.y >> 16)) - mf);
        ssum += (e0 + e1) + (e2 + e3);
        uint u0 = (uint)f2bf(e0) | ((uint)f2bf(e1) << 16);
        uint u1 = (uint)f2bf(e2) | ((uint)f2bf(e3) << 16);
        *(uint2*)(raw + byteoff) = make_uint2(u0, u1);
    }
    ssum += __shfl_xor(ssum, 16);
    ssum += __shfl_xor(ssum, 32);
    if (l < 16) smv[kh * 32 + qh * 16 + l] = ssum;
    __syncthreads();
    if (t < 32) invb[t] = 1.0f / (smv[t] + smv[32 + t]);
    __syncthreads();

    for (int rr = 0; rr < 32; ++rr) {
        uint byteoff = (uint)rr * 2048u + (((uint)t * 8u) ^ (((uint)(rr & 7)) << 4));
        uint2 v = *(uint2*)(raw + byteoff);
        float inv = invb[rr];
        float4 o;
        o.x = bf2f((ushort)(v.x & 0xFFFF)) * inv;
        o.y = bf2f((ushort)(v.x >> 16)) * inv;
        o.z = bf2f((ushort)(v.y & 0xFFFF)) * inv;
        o.w = bf2f((ushort)(v.y >> 16)) * inv;
        *(float4*)(attn + (((size_t)b * NL + q0 + rr) * NH + h) * NL + (size_t)t * 4) = o;
    }

    f32x4 acc0 = {0.f,0.f,0.f,0.f}, acc1 = {0.f,0.f,0.f,0.f};
    f32x4 acc2 = {0.f,0.f,0.f,0.f}, acc3 = {0.f,0.f,0.f,0.f};
    for (int kc = 0; kc < 16; ++kc) {
        const int kchunk = kh * 512 + kc * 32;
        short8 pa = *(short8*)(raw + (uint)qr * 2048u + ((((uint)(kchunk + hi * 8)) * 2u) ^ swz));
        short8 b0 = *(const short8*)(vT + ((size_t)(b * NDK +  0 + lo)) * NL + kchunk + hi * 8);
        short8 b1 = *(const short8*)(vT + ((size_t)(b * NDK + 16 + lo)) * NL + kchunk + hi * 8);
        short8 b2 = *(const short8*)(vT + ((size_t)(b * NDK + 32 + lo)) * NL + kchunk + hi * 8);
        short8 b3 = *(const short8*)(vT + ((size_t)(b * NDK + 48 + lo)) * NL + kchunk + hi * 8);
        acc0 = __builtin_amdgcn_mfma_f32_16x16x32_bf16(pa, b0, acc0, 0, 0, 0);
        acc1 = __builtin_amdgcn_mfma_f32_16x16x32_bf16(pa, b1, acc1, 0, 0, 0);
        acc2 = __builtin_amdgcn_mfma_f32_16x16x32_bf16(pa, b2, acc2, 0, 0, 0);
        acc3 = __builtin_amdgcn_mfma_f32_16x16x32_bf16(pa, b3, acc3, 0, 0, 0);
    }
    __syncthreads();
    float* pvp = (float*)raw;
    #pragma unroll
    for (int r = 0; r < 4; ++r) {
        int qq = qh * 16 + hi * 4 + r;
        pvp[(kh * 32 + qq) * 64 +  0 + lo] = acc0[r];
        pvp[(kh * 32 + qq) * 64 + 16 + lo] = acc1[r];
        pvp[(kh * 32 + qq) * 64 + 32 + lo] = acc2[r];
        pvp[(kh * 32 + qq) * 64 + 48 + lo] = acc3[r];
    }
    __syncthreads();
    #pragma unroll
    for (int i = 0; i < 8; ++i) {
        int idx = t + 256 * i;
        int qq = idx >> 6, vv = idx & 63;
        float s2 = pvp[idx] + pvp[idx + 2048];
        heads[(bh + q0 + qq) * NDK + vv] = s2 * invb[qq];
    }
}

// ---------------------------------------------------------------------------
__global__ __launch_bounds__(256) void mean_kernel(
    const float* __restrict__ heads, float* __restrict__ hm)
{
    int id = blockIdx.x * 256 + threadIdx.x;
    int b = id >> 14;
    int r = id & 16383;
    const float4* src = (const float4*)heads;
    float sx = 0.f, sy = 0.f, sz = 0.f, sw = 0.f;
    #pragma unroll
    for (int h2 = 0; h2 < 16; ++h2) {
        float4 v = src[(((size_t)b * 16 + h2) << 14) + r];
        sx += v.x; sy += v.y; sz += v.z; sw += v.w;
    }
    float4 o; o.x = sx * 0.0625f; o.y = sy * 0.0625f; o.z = sz * 0.0625f; o.w = sw * 0.0625f;
    ((float4*)hm)[(((size_t)b) << 14) + r] = o;
}

// ---------------------------------------------------------------------------
__global__ __launch_bounds__(256) void out_proj_kernel(
    const float* __restrict__ head_mean, const float* __restrict__ wo,
    const float* __restrict__ bo, float* __restrict__ out)
{
    const int t = threadIdx.x;
    const int row0 = blockIdx.x * 8;
    __shared__ float hm[8][64];
    if (t < 128) {
        int r = t >> 4;
        int c = (t & 15) * 4;
        *(float4*)&hm[r][c] = *(const float4*)&head_mean[((size_t)row0 + r) * NDK + c];
    }
    __syncthreads();

    float acc[8][4];
    #pragma unroll
    for (int r = 0; r < 8; ++r)
        #pragma unroll
        for (int j = 0; j < 4; ++j) acc[r][j] = 0.f;

    for (int k = 0; k < 64; ++k) {
        float w0 = wo[(size_t)k * ND + t];
        float w1 = wo[(size_t)k * ND + t + 256];
        float w2 = wo[(size_t)k * ND + t + 512];
        float w3 = wo[(size_t)k * ND + t + 768];
        #pragma unroll
        for (int r = 0; r < 8; ++r) {
            float hv = hm[r][k];
            acc[r][0] += hv * w0;
            acc[r][1] += hv * w1;
            acc[r][2] += hv * w2;
            acc[r][3] += hv * w3;
        }
    }
    #pragma unroll
    for (int r = 0; r < 8; ++r) {
        out[((size_t)row0 + r) * ND + t      ] = acc[r][0] + bo[t];
        out[((size_t)row0 + r) * ND + t + 256] = acc[r][1] + bo[t + 256];
        out[((size_t)row0 + r) * ND + t + 512] = acc[r][2] + bo[t + 512];
        out[((size_t)row0 + r) * ND + t + 768] = acc[r][3] + bo[t + 768];
    }
}

// ---------------------------------------------------------------------------
extern "C" void kernel_launch(void* const* d_in, const int* in_sizes, int n_in,
                              void* d_out, int out_size, void* d_ws, size_t ws_size,
                              hipStream_t stream) {
    const float* query  = (const float*)d_in[0];
    const float* key_in = (const float*)d_in[1];
    const float* value  = (const float*)d_in[2];
    const float* wq     = (const float*)d_in[3];
    const float* bq     = (const float*)d_in[4];
    const float* wk     = (const float*)d_in[5];
    const float* bk     = (const float*)d_in[6];
    const float* wv     = (const float*)d_in[7];
    const float* bv     = (const float*)d_in[8];
    const float* wo     = (const float*)d_in[9];
    const float* bo     = (const float*)d_in[10];

    float* out  = (float*)d_out;                       // [B, L, D]
    float* attn = out + (size_t)NB * NL * ND;          // [B, L, H, L]

    ushort* wqT    = (ushort*)d_ws;                               // 1024*1024
    ushort* wkT    = wqT + (size_t)ND * NH * NDK;                 // 1024*1024
    ushort* wvT    = wkT + (size_t)ND * NH * NDK;                 // 128*1024 (padded)
    ushort* q_all  = wvT + (size_t)128 * ND;                      // B*H*L*DK
    ushort* k_all  = q_all + (size_t)NB * NH * NL * NDK;
    ushort* v_proj = k_all + (size_t)NB * NH * NL * NDK;          // B*L*DK
    ushort* vT     = v_proj + (size_t)NB * NL * NDK;              // B*DK*L
    float*  heads  = (float*)(vT + (size_t)NB * NL * NDK);        // B*H*L*DK f32
    float*  head_mean = heads + (size_t)NB * NH * NL * NDK;       // B*L*DK f32

    cvtw_kernel<<<dim3(16, 33), 256, 0, stream>>>(wq, wk, wv, wqT, wkT, wvT);
    proj_gemm<<<dim3(544), 256, 0, stream>>>(
        query, key_in, value, wqT, wkT, wvT, bq, bk, bv, q_all, k_all, v_proj);
    vtrans_kernel<<<dim3(16, NB), 256, 0, stream>>>(v_proj, vT);
    attn_mfma_kernel<<<dim3(32, NH, NB), 256, 0, stream>>>(
        q_all, k_all, vT, attn, heads);
    mean_kernel<<<dim3(256), 256, 0, stream>>>(heads, head_mean);
    out_proj_kernel<<<dim3(NB * NL / 8), 256, 0, stream>>>(
        head_mean, wo, bo, out);
}

// Round 4
// 241.003 us; speedup vs baseline: 7.8421x; 1.0753x over previous
//
#include <hip/hip_runtime.h>
#include <math.h>

// Problem constants (B=4, L=1024, D=1024, H=16, DK=64)
#define NB 4
#define NL 1024
#define ND 1024
#define NH 16
#define NDK 64

typedef __attribute__((ext_vector_type(8))) short short8;
typedef __attribute__((ext_vector_type(4))) float f32x4;

__device__ inline ushort f2bf(float f) {
    uint x = __float_as_uint(f);
    x += 0x7FFFu + ((x >> 16) & 1u);   // RNE
    return (ushort)(x >> 16);
}
__device__ inline float bf2f(ushort u) { return __uint_as_float(((uint)u) << 16); }

// ---------------------------------------------------------------------------
// Weight cvt+transpose: wqT[h*64+dk][d] = bf16(wq[h][d][dk])  (B^T layout)
// y<16: wq head y; y<32: wk head y-16; y==32: wv (+zero rows 64..127 of wvT).
// ---------------------------------------------------------------------------
__global__ __launch_bounds__(256) void cvtw_kernel(
    const float* __restrict__ wq, const float* __restrict__ wk,
    const float* __restrict__ wv,
    ushort* __restrict__ wqT, ushort* __restrict__ wkT, ushort* __restrict__ wvT)
{
    __shared__ ushort tl[64][72];
    const int t = threadIdx.x;
    const int d0 = blockIdx.x * 64;
    const int y = blockIdx.y;
    const float* src; ushort* dst; int h;
    if (y < 16)      { src = wq + (size_t)y * ND * NDK;        dst = wqT; h = y; }
    else if (y < 32) { src = wk + (size_t)(y - 16) * ND * NDK; dst = wkT; h = y - 16; }
    else             { src = wv;                               dst = wvT; h = 0; }

    int r = t >> 2, c0 = (t & 3) * 16;
    const float* s = src + (size_t)(d0 + r) * NDK + c0;
    #pragma unroll
    for (int j = 0; j < 16; j += 4) {
        float4 v = *(const float4*)(s + j);
        tl[c0 + j + 0][r] = f2bf(v.x);
        tl[c0 + j + 1][r] = f2bf(v.y);
        tl[c0 + j + 2][r] = f2bf(v.z);
        tl[c0 + j + 3][r] = f2bf(v.w);
    }
    __syncthreads();
    int vv = t >> 2, lc = (t & 3) * 16;
    ushort* d = dst + ((size_t)h * 64 + vv) * ND + d0 + lc;
    #pragma unroll
    for (int j = 0; j < 16; j += 8) {
        short8 o;
        #pragma unroll
        for (int e = 0; e < 8; ++e) o[e] = (short)tl[vv][lc + j + e];
        *(short8*)(d + j) = o;
    }
    if (y == 32) {
        ushort* zp = wvT + ((size_t)(64 + (t >> 2))) * ND + d0 + (t & 3) * 16;
        short8 z8 = {0,0,0,0,0,0,0,0};
        *(short8*)(zp) = z8;
        *(short8*)(zp + 8) = z8;
    }
}

// ---------------------------------------------------------------------------
// MFMA projection GEMM. 128x128 tile, BK=64, 4 waves (2x2 of 64x64).
// A = fp32 rows (cvt->bf16 in reg-staging); B = bf16 [N][K] weights.
// LDS XOR-swizzled (byte ^= (row&7)<<4). Epilogue restages C through LDS
// for short8 coalesced stores; z==2 writes vT[b][dk][l] directly.
// Grid 544 = 8*68 XCD-chunked bijective swizzle.
// ---------------------------------------------------------------------------
__global__ __launch_bounds__(256) void proj_gemm(
    const float* __restrict__ query, const float* __restrict__ key_in,
    const float* __restrict__ value,
    const ushort* __restrict__ wqT, const ushort* __restrict__ wkT,
    const ushort* __restrict__ wvT,
    const float* __restrict__ bq, const float* __restrict__ bk,
    const float* __restrict__ bv,
    ushort* __restrict__ q_all, ushort* __restrict__ k_all,
    ushort* __restrict__ vT)
{
    __shared__ char lds[32768];   // A bf16 [128][64] @0 ; B bf16 [128][64] @16384

    int id = blockIdx.x;
    int wg = (id & 7) * 68 + (id >> 3);   // 544 = 8 XCDs x 68, bijective
    int z, mt, nt;
    if (wg < 512) { z = wg >> 8; int rem = wg & 255; mt = rem >> 3; nt = rem & 7; }
    else          { z = 2; mt = wg - 512; nt = 0; }

    const float* A; const ushort* Bw; const float* bias; float scale;
    if (z == 0)      { A = query;  Bw = wqT; bias = bq; scale = 0.125f; }
    else if (z == 1) { A = key_in; Bw = wkT; bias = bk; scale = 1.0f; }
    else             { A = value;  Bw = wvT; bias = bv; scale = 1.0f; }
    ushort* C = (z == 0) ? q_all : k_all;

    const int t = threadIdx.x;
    const int w = t >> 6, l = t & 63;
    const int lo16 = l & 15, hi = l >> 4;
    const int wm = w >> 1, wn = w & 1;
    const int m0 = mt * 128, n0 = nt * 128;

    f32x4 acc[4][4];
    #pragma unroll
    for (int mi = 0; mi < 4; ++mi)
        #pragma unroll
        for (int ni = 0; ni < 4; ++ni) acc[mi][ni] = (f32x4){0.f, 0.f, 0.f, 0.f};

    const int a_r = t >> 4, a_f4 = t & 15;
    const int b_r = t >> 3, b_k8 = t & 7;

    for (int kt = 0; kt < 16; ++kt) {
        const int k0 = kt * 64;
        __syncthreads();
        #pragma unroll
        for (int i = 0; i < 8; ++i) {
            int row = a_r + 16 * i;
            float4 v = *(const float4*)(A + (size_t)(m0 + row) * ND + k0 + a_f4 * 4);
            uint u0 = (uint)f2bf(v.x) | ((uint)f2bf(v.y) << 16);
            uint u1 = (uint)f2bf(v.z) | ((uint)f2bf(v.w) << 16);
            uint off = ((uint)row * 128u + (uint)a_f4 * 8u) ^ (((uint)(row & 7)) << 4);
            *(uint2*)(lds + off) = make_uint2(u0, u1);
        }
        #pragma unroll
        for (int i = 0; i < 4; ++i) {
            int row = b_r + 32 * i;
            short8 v = *(const short8*)(Bw + (size_t)(n0 + row) * ND + k0 + b_k8 * 8);
            uint off = ((uint)row * 128u + (uint)b_k8 * 16u) ^ (((uint)(row & 7)) << 4);
            *(short8*)(lds + 16384 + off) = v;
        }
        __syncthreads();
        #pragma unroll
        for (int ks = 0; ks < 2; ++ks) {
            short8 Af[4], Bf[4];
            #pragma unroll
            for (int mi = 0; mi < 4; ++mi) {
                int row = wm * 64 + mi * 16 + lo16;
                uint off = ((uint)row * 128u + (uint)(ks * 64 + hi * 16)) ^ (((uint)(row & 7)) << 4);
                Af[mi] = *(short8*)(lds + off);
            }
            #pragma unroll
            for (int ni = 0; ni < 4; ++ni) {
                int row = wn * 64 + ni * 16 + lo16;
                uint off = ((uint)row * 128u + (uint)(ks * 64 + hi * 16)) ^ (((uint)(row & 7)) << 4);
                Bf[ni] = *(short8*)(lds + 16384 + off);
            }
            #pragma unroll
            for (int mi = 0; mi < 4; ++mi)
                #pragma unroll
                for (int ni = 0; ni < 4; ++ni)
                    acc[mi][ni] = __builtin_amdgcn_mfma_f32_16x16x32_bf16(
                        Af[mi], Bf[ni], acc[mi][ni], 0, 0, 0);
        }
    }

    // D frag: row = hi*4 + r (+16*mi), col = lo16 (+16*ni).
    if (z == 2) {
        // vT[b][dk][l] direct: r-index is contiguous in l -> pack uint2.
        if (wn == 0) {
            #pragma unroll
            for (int ni = 0; ni < 4; ++ni) {
                int n = ni * 16 + lo16;          // dk 0..63
                float bs = bias[n];
                #pragma unroll
                for (int mi = 0; mi < 4; ++mi) {
                    int mbase = m0 + wm * 64 + mi * 16 + hi * 4;
                    int b = mbase >> 10, ll = mbase & 1023;
                    uint u0 = (uint)f2bf(acc[mi][ni][0] + bs) | ((uint)f2bf(acc[mi][ni][1] + bs) << 16);
                    uint u1 = (uint)f2bf(acc[mi][ni][2] + bs) | ((uint)f2bf(acc[mi][ni][3] + bs) << 16);
                    *(uint2*)(vT + ((size_t)b * NDK + n) * NL + ll) = make_uint2(u0, u1);
                }
            }
        }
        return;
    }

    // z<2: restage C tile in LDS (bf16 [128][128] = 32KB), then short8 stores.
    __syncthreads();
    ushort* cst = (ushort*)lds;
    const int n0w = wn * 64;
    #pragma unroll
    for (int ni = 0; ni < 4; ++ni) {
        int nl = n0w + ni * 16 + lo16;
        float bs = bias[n0 + nl];
        #pragma unroll
        for (int mi = 0; mi < 4; ++mi) {
            int mlb = wm * 64 + mi * 16 + hi * 4;
            #pragma unroll
            for (int r = 0; r < 4; ++r)
                cst[(mlb + r) * 128 + nl] = f2bf((acc[mi][ni][r] + bs) * scale);
        }
    }
    __syncthreads();
    #pragma unroll
    for (int i = 0; i < 8; ++i) {
        int unit = t + 256 * i;               // 0..2047
        int row = unit >> 4, s8 = unit & 15;
        short8 v = *(short8*)(cst + row * 128 + s8 * 8);
        int m = m0 + row, n = n0 + s8 * 8;
        int b = m >> 10, ll = m & 1023, h = n >> 6, dk = n & 63;
        *(short8*)(C + (((size_t)b * NH + h) * NL + ll) * NDK + dk) = v;
    }
}

// ---------------------------------------------------------------------------
// Stage 2: MFMA attention (unchanged — verified rounds 2-3).
// ---------------------------------------------------------------------------
__global__ __launch_bounds__(256) void attn_mfma_kernel(
    const ushort* __restrict__ q_all, const ushort* __restrict__ k_all,
    const ushort* __restrict__ vT,
    float* __restrict__ attn, float* __restrict__ heads)
{
    __shared__ char raw[65536 + 640];
    float* mx   = (float*)(raw + 65536);
    float* smv  = (float*)(raw + 65536 + 256);
    float* invb = (float*)(raw + 65536 + 512);

    const int t = threadIdx.x;
    const int w = t >> 6, l = t & 63;
    const int hi = l >> 4, lo = l & 15;
    const int qh = w & 1, kh = w >> 1;
    const int q0 = blockIdx.x * 32;
    const int h  = blockIdx.y;
    const int b  = blockIdx.z;
    const size_t bh = ((size_t)b * NH + h) * NL;

    const int qr = qh * 16 + lo;
    const uint swz = ((uint)(qr & 7)) << 4;

    short8 Qb0 = *(const short8*)(q_all + (bh + q0 + qr) * NDK + hi * 8);
    short8 Qb1 = *(const short8*)(q_all + (bh + q0 + qr) * NDK + 32 + hi * 8);

    float mmax = -3.0e38f;
    for (int kt = 0; kt < 32; ++kt) {
        const int kbase = kh * 512 + kt * 16;
        short8 Ka0 = *(const short8*)(k_all + (bh + kbase + lo) * NDK + hi * 8);
        short8 Ka1 = *(const short8*)(k_all + (bh + kbase + lo) * NDK + 32 + hi * 8);
        f32x4 s = {0.f, 0.f, 0.f, 0.f};
        s = __builtin_amdgcn_mfma_f32_16x16x32_bf16(Ka0, Qb0, s, 0, 0, 0);
        s = __builtin_amdgcn_mfma_f32_16x16x32_bf16(Ka1, Qb1, s, 0, 0, 0);
        mmax = fmaxf(mmax, fmaxf(fmaxf(s[0], s[1]), fmaxf(s[2], s[3])));
        uint u0 = (uint)f2bf(s[0]) | ((uint)f2bf(s[1]) << 16);
        uint u1 = (uint)f2bf(s[2]) | ((uint)f2bf(s[3]) << 16);
        uint byteoff = (uint)qr * 2048u + ((((uint)(kbase + hi * 4)) * 2u) ^ swz);
        *(uint2*)(raw + byteoff) = make_uint2(u0, u1);
    }
    mmax = fmaxf(mmax, __shfl_xor(mmax, 16));
    mmax = fmaxf(mmax, __shfl_xor(mmax, 32));
    if (l < 16) mx[kh * 32 + qh * 16 + l] = mmax;
    __syncthreads();
    const float mf = fmaxf(mx[qr], mx[32 + qr]);

    float ssum = 0.f;
    for (int kt = 0; kt < 32; ++kt) {
        const int kbase = kh * 512 + kt * 16;
        uint byteoff = (uint)qr * 2048u + ((((uint)(kbase + hi * 4)) * 2u) ^ swz);
        uint2 v = *(uint2*)(raw + byteoff);
        float e0 = __expf(bf2f((ushort)(v.x & 0xFFFF)) - mf);
        float e1 = __expf(bf2f((ushort)(v.x >> 16)) - mf);
        float e2 = __expf(bf2f((ushort)(v.y & 0xFFFF)) - mf);
        float e3 = __expf(bf2f((ushort)(v.y >> 16)) - mf);
        ssum += (e0 + e1) + (e2 + e3);
        uint u0 = (uint)f2bf(e0) | ((uint)f2bf(e1) << 16);
        uint u1 = (uint)f2bf(e2) | ((uint)f2bf(e3) << 16);
        *(uint2*)(raw + byteoff) = make_uint2(u0, u1);
    }
    ssum += __shfl_xor(ssum, 16);
    ssum += __shfl_xor(ssum, 32);
    if (l < 16) smv[kh * 32 + qh * 16 + l] = ssum;
    __syncthreads();
    if (t < 32) invb[t] = 1.0f / (smv[t] + smv[32 + t]);
    __syncthreads();

    for (int rr = 0; rr < 32; ++rr) {
        uint byteoff = (uint)rr * 2048u + (((uint)t * 8u) ^ (((uint)(rr & 7)) << 4));
        uint2 v = *(uint2*)(raw + byteoff);
        float inv = invb[rr];
        float4 o;
        o.x = bf2f((ushort)(v.x & 0xFFFF)) * inv;
        o.y = bf2f((ushort)(v.x >> 16)) * inv;
        o.z = bf2f((ushort)(v.y & 0xFFFF)) * inv;
        o.w = bf2f((ushort)(v.y >> 16)) * inv;
        *(float4*)(attn + (((size_t)b * NL + q0 + rr) * NH + h) * NL + (size_t)t * 4) = o;
    }

    f32x4 acc0 = {0.f,0.f,0.f,0.f}, acc1 = {0.f,0.f,0.f,0.f};
    f32x4 acc2 = {0.f,0.f,0.f,0.f}, acc3 = {0.f,0.f,0.f,0.f};
    for (int kc = 0; kc < 16; ++kc) {
        const int kchunk = kh * 512 + kc * 32;
        short8 pa = *(short8*)(raw + (uint)qr * 2048u + ((((uint)(kchunk + hi * 8)) * 2u) ^ swz));
        short8 b0 = *(const short8*)(vT + ((size_t)(b * NDK +  0 + lo)) * NL + kchunk + hi * 8);
        short8 b1 = *(const short8*)(vT + ((size_t)(b * NDK + 16 + lo)) * NL + kchunk + hi * 8);
        short8 b2 = *(const short8*)(vT + ((size_t)(b * NDK + 32 + lo)) * NL + kchunk + hi * 8);
        short8 b3 = *(const short8*)(vT + ((size_t)(b * NDK + 48 + lo)) * NL + kchunk + hi * 8);
        acc0 = __builtin_amdgcn_mfma_f32_16x16x32_bf16(pa, b0, acc0, 0, 0, 0);
        acc1 = __builtin_amdgcn_mfma_f32_16x16x32_bf16(pa, b1, acc1, 0, 0, 0);
        acc2 = __builtin_amdgcn_mfma_f32_16x16x32_bf16(pa, b2, acc2, 0, 0, 0);
        acc3 = __builtin_amdgcn_mfma_f32_16x16x32_bf16(pa, b3, acc3, 0, 0, 0);
    }
    __syncthreads();
    float* pvp = (float*)raw;
    #pragma unroll
    for (int r = 0; r < 4; ++r) {
        int qq = qh * 16 + hi * 4 + r;
        pvp[(kh * 32 + qq) * 64 +  0 + lo] = acc0[r];
        pvp[(kh * 32 + qq) * 64 + 16 + lo] = acc1[r];
        pvp[(kh * 32 + qq) * 64 + 32 + lo] = acc2[r];
        pvp[(kh * 32 + qq) * 64 + 48 + lo] = acc3[r];
    }
    __syncthreads();
    #pragma unroll
    for (int i = 0; i < 8; ++i) {
        int idx = t + 256 * i;
        int qq = idx >> 6, vv = idx & 63;
        float s2 = pvp[idx] + pvp[idx + 2048];
        heads[(bh + q0 + qq) * NDK + vv] = s2 * invb[qq];
    }
}

// ---------------------------------------------------------------------------
// Stage 3: head-mean (inline) + output projection.
// hm[r][k] = (1/16) sum_h heads[b,h,l0+r,k]; out = hm @ wo + bo.
// ---------------------------------------------------------------------------
__global__ __launch_bounds__(256) void out_proj_kernel(
    const float* __restrict__ heads, const float* __restrict__ wo,
    const float* __restrict__ bo, float* __restrict__ out)
{
    const int t = threadIdx.x;
    const int row0 = blockIdx.x * 8;          // global row (b*1024 + l)
    const int b = row0 >> 10, l0 = row0 & 1023;
    __shared__ float hm[8][64];
    if (t < 128) {
        int r = t >> 4;
        int f4 = t & 15;
        float sx = 0.f, sy = 0.f, sz = 0.f, sw = 0.f;
        #pragma unroll
        for (int h = 0; h < 16; ++h) {
            float4 v = *(const float4*)&heads[(((size_t)b * NH + h) * NL + l0 + r) * NDK + f4 * 4];
            sx += v.x; sy += v.y; sz += v.z; sw += v.w;
        }
        float4 o; o.x = sx * 0.0625f; o.y = sy * 0.0625f; o.z = sz * 0.0625f; o.w = sw * 0.0625f;
        *(float4*)&hm[r][f4 * 4] = o;
    }
    __syncthreads();

    float acc[8][4];
    #pragma unroll
    for (int r = 0; r < 8; ++r)
        #pragma unroll
        for (int j = 0; j < 4; ++j) acc[r][j] = 0.f;

    for (int k = 0; k < 64; ++k) {
        float w0 = wo[(size_t)k * ND + t];
        float w1 = wo[(size_t)k * ND + t + 256];
        float w2 = wo[(size_t)k * ND + t + 512];
        float w3 = wo[(size_t)k * ND + t + 768];
        #pragma unroll
        for (int r = 0; r < 8; ++r) {
            float hv = hm[r][k];
            acc[r][0] += hv * w0;
            acc[r][1] += hv * w1;
            acc[r][2] += hv * w2;
            acc[r][3] += hv * w3;
        }
    }
    #pragma unroll
    for (int r = 0; r < 8; ++r) {
        out[((size_t)row0 + r) * ND + t      ] = acc[r][0] + bo[t];
        out[((size_t)row0 + r) * ND + t + 256] = acc[r][1] + bo[t + 256];
        out[((size_t)row0 + r) * ND + t + 512] = acc[r][2] + bo[t + 512];
        out[((size_t)row0 + r) * ND + t + 768] = acc[r][3] + bo[t + 768];
    }
}

// ---------------------------------------------------------------------------
extern "C" void kernel_launch(void* const* d_in, const int* in_sizes, int n_in,
                              void* d_out, int out_size, void* d_ws, size_t ws_size,
                              hipStream_t stream) {
    const float* query  = (const float*)d_in[0];
    const float* key_in = (const float*)d_in[1];
    const float* value  = (const float*)d_in[2];
    const float* wq     = (const float*)d_in[3];
    const float* bq     = (const float*)d_in[4];
    const float* wk     = (const float*)d_in[5];
    const float* bk     = (const float*)d_in[6];
    const float* wv     = (const float*)d_in[7];
    const float* bv     = (const float*)d_in[8];
    const float* wo     = (const float*)d_in[9];
    const float* bo     = (const float*)d_in[10];

    float* out  = (float*)d_out;                       // [B, L, D]
    float* attn = out + (size_t)NB * NL * ND;          // [B, L, H, L]

    ushort* wqT    = (ushort*)d_ws;                               // 1024*1024
    ushort* wkT    = wqT + (size_t)ND * NH * NDK;                 // 1024*1024
    ushort* wvT    = wkT + (size_t)ND * NH * NDK;                 // 128*1024 (padded)
    ushort* q_all  = wvT + (size_t)128 * ND;                      // B*H*L*DK
    ushort* k_all  = q_all + (size_t)NB * NH * NL * NDK;
    ushort* vT     = k_all + (size_t)NB * NH * NL * NDK;          // B*DK*L
    float*  heads  = (float*)(vT + (size_t)NB * NDK * NL);        // B*H*L*DK f32

    cvtw_kernel<<<dim3(16, 33), 256, 0, stream>>>(wq, wk, wv, wqT, wkT, wvT);
    proj_gemm<<<dim3(544), 256, 0, stream>>>(
        query, key_in, value, wqT, wkT, wvT, bq, bk, bv, q_all, k_all, vT);
    attn_mfma_kernel<<<dim3(32, NH, NB), 256, 0, stream>>>(
        q_all, k_all, vT, attn, heads);
    out_proj_kernel<<<dim3(NB * NL / 8), 256, 0, stream>>>(
        heads, wo, bo, out);
}

// Round 5
// 229.885 us; speedup vs baseline: 8.2213x; 1.0484x over previous
//
#include <hip/hip_runtime.h>
#include <math.h>

// Problem constants (B=4, L=1024, D=1024, H=16, DK=64)
#define NB 4
#define NL 1024
#define ND 1024
#define NH 16
#define NDK 64

typedef __attribute__((ext_vector_type(8))) short short8;
typedef __attribute__((ext_vector_type(4))) float f32x4;

__device__ inline ushort f2bf(float f) {
    uint x = __float_as_uint(f);
    x += 0x7FFFu + ((x >> 16) & 1u);   // RNE
    return (ushort)(x >> 16);
}
__device__ inline float bf2f(ushort u) { return __uint_as_float(((uint)u) << 16); }

__device__ inline void gload16(const void* g, void* l) {
    __builtin_amdgcn_global_load_lds(
        (const __attribute__((address_space(1))) void*)g,
        (__attribute__((address_space(3))) void*)l, 16, 0, 0);
}

// ---------------------------------------------------------------------------
// Input cvt: bf16(query|key|value) -> abf[y]  (y = 0,1,2)
// ---------------------------------------------------------------------------
__global__ __launch_bounds__(256) void cvt_in_kernel(
    const float* __restrict__ q, const float* __restrict__ k,
    const float* __restrict__ v, ushort* __restrict__ abf)
{
    const float* src = (blockIdx.y == 0) ? q : (blockIdx.y == 1) ? k : v;
    size_t base = ((size_t)blockIdx.x * 256 + threadIdx.x) * 8;
    float4 a = *(const float4*)(src + base);
    float4 b = *(const float4*)(src + base + 4);
    short8 o;
    o[0] = (short)f2bf(a.x); o[1] = (short)f2bf(a.y);
    o[2] = (short)f2bf(a.z); o[3] = (short)f2bf(a.w);
    o[4] = (short)f2bf(b.x); o[5] = (short)f2bf(b.y);
    o[6] = (short)f2bf(b.z); o[7] = (short)f2bf(b.w);
    *(short8*)(abf + (size_t)blockIdx.y * (NB * NL * ND) + base) = o;
}

// ---------------------------------------------------------------------------
// Weight cvt+transpose: wqT[h*64+dk][d] = bf16(wq[h][d][dk])  (B^T layout)
// y<16: wq head y; y<32: wk head y-16; y==32: wv (+zero rows 64..127 of wvT).
// ---------------------------------------------------------------------------
__global__ __launch_bounds__(256) void cvtw_kernel(
    const float* __restrict__ wq, const float* __restrict__ wk,
    const float* __restrict__ wv,
    ushort* __restrict__ wqT, ushort* __restrict__ wkT, ushort* __restrict__ wvT)
{
    __shared__ ushort tl[64][72];
    const int t = threadIdx.x;
    const int d0 = blockIdx.x * 64;
    const int y = blockIdx.y;
    const float* src; ushort* dst; int h;
    if (y < 16)      { src = wq + (size_t)y * ND * NDK;        dst = wqT; h = y; }
    else if (y < 32) { src = wk + (size_t)(y - 16) * ND * NDK; dst = wkT; h = y - 16; }
    else             { src = wv;                               dst = wvT; h = 0; }

    int r = t >> 2, c0 = (t & 3) * 16;
    const float* s = src + (size_t)(d0 + r) * NDK + c0;
    #pragma unroll
    for (int j = 0; j < 16; j += 4) {
        float4 v = *(const float4*)(s + j);
        tl[c0 + j + 0][r] = f2bf(v.x);
        tl[c0 + j + 1][r] = f2bf(v.y);
        tl[c0 + j + 2][r] = f2bf(v.z);
        tl[c0 + j + 3][r] = f2bf(v.w);
    }
    __syncthreads();
    int vv = t >> 2, lc = (t & 3) * 16;
    ushort* d = dst + ((size_t)h * 64 + vv) * ND + d0 + lc;
    #pragma unroll
    for (int j = 0; j < 16; j += 8) {
        short8 o;
        #pragma unroll
        for (int e = 0; e < 8; ++e) o[e] = (short)tl[vv][lc + j + e];
        *(short8*)(d + j) = o;
    }
    if (y == 32) {
        ushort* zp = wvT + ((size_t)(64 + (t >> 2))) * ND + d0 + (t & 3) * 16;
        short8 z8 = {0,0,0,0,0,0,0,0};
        *(short8*)(zp) = z8;
        *(short8*)(zp + 8) = z8;
    }
}

// ---------------------------------------------------------------------------
// MFMA projection GEMM. 128x128 tile, BK=64, 4 waves (2x2 of 64x64).
// A,B bf16 staged via global_load_lds width-16; LDS dest linear, source
// pre-swizzled so content lands XOR-swizzled (byte ^= (row&7)<<4) — readers
// unchanged. Epilogue restages C through LDS for short8 coalesced stores;
// z==2 writes vT[b][dk][l] directly. Grid 544 = 8*68 XCD-chunked bijective.
// ---------------------------------------------------------------------------
__global__ __launch_bounds__(256) void proj_gemm(
    const ushort* __restrict__ abf,
    const ushort* __restrict__ wqT, const ushort* __restrict__ wkT,
    const ushort* __restrict__ wvT,
    const float* __restrict__ bq, const float* __restrict__ bk,
    const float* __restrict__ bv,
    ushort* __restrict__ q_all, ushort* __restrict__ k_all,
    ushort* __restrict__ vT)
{
    __shared__ char lds[32768];   // A bf16 [128][64] @0 ; B bf16 [128][64] @16384

    int id = blockIdx.x;
    int wg = (id & 7) * 68 + (id >> 3);   // 544 = 8 XCDs x 68, bijective
    int z, mt, nt;
    if (wg < 512) { z = wg >> 8; int rem = wg & 255; mt = rem >> 3; nt = rem & 7; }
    else          { z = 2; mt = wg - 512; nt = 0; }

    const ushort* A; const ushort* Bw; const float* bias; float scale;
    if (z == 0)      { A = abf;                 Bw = wqT; bias = bq; scale = 0.125f; }
    else if (z == 1) { A = abf + NB * NL * ND;  Bw = wkT; bias = bk; scale = 1.0f; }
    else             { A = abf + 2 * NB * NL * ND; Bw = wvT; bias = bv; scale = 1.0f; }
    ushort* C = (z == 0) ? q_all : k_all;

    const int t = threadIdx.x;
    const int w = t >> 6, l = t & 63;
    const int lo16 = l & 15, hi = l >> 4;
    const int wm = w >> 1, wn = w & 1;
    const int m0 = mt * 128, n0 = nt * 128;

    f32x4 acc[4][4];
    #pragma unroll
    for (int mi = 0; mi < 4; ++mi)
        #pragma unroll
        for (int ni = 0; ni < 4; ++ni) acc[mi][ni] = (f32x4){0.f, 0.f, 0.f, 0.f};

    // stager geometry: slab s = w*4+i covers LDS bytes [s*1024,(s+1)*1024);
    // lane l -> physical byte s*1024 + l*16 = row s*8+(l>>3), inv-swz col.
    int rS[4]; uint cS[4];
    #pragma unroll
    for (int i = 0; i < 4; ++i) {
        int s = w * 4 + i;
        int row = s * 8 + (l >> 3);
        rS[i] = row;
        cS[i] = (((uint)(l & 7)) * 16u) ^ (((uint)(row & 7)) << 4);
    }

    for (int kt = 0; kt < 16; ++kt) {
        const int k0 = kt * 64;
        __syncthreads();
        #pragma unroll
        for (int i = 0; i < 4; ++i) {
            int s = w * 4 + i;
            gload16(A + (size_t)(m0 + rS[i]) * ND + k0 + (cS[i] >> 1), lds + s * 1024);
            gload16(Bw + (size_t)(n0 + rS[i]) * ND + k0 + (cS[i] >> 1), lds + 16384 + s * 1024);
        }
        __syncthreads();   // drains vmcnt -> LDS tiles valid
        #pragma unroll
        for (int ks = 0; ks < 2; ++ks) {
            short8 Af[4], Bf[4];
            #pragma unroll
            for (int mi = 0; mi < 4; ++mi) {
                int row = wm * 64 + mi * 16 + lo16;
                uint off = ((uint)row * 128u + (uint)(ks * 64 + hi * 16)) ^ (((uint)(row & 7)) << 4);
                Af[mi] = *(short8*)(lds + off);
            }
            #pragma unroll
            for (int ni = 0; ni < 4; ++ni) {
                int row = wn * 64 + ni * 16 + lo16;
                uint off = ((uint)row * 128u + (uint)(ks * 64 + hi * 16)) ^ (((uint)(row & 7)) << 4);
                Bf[ni] = *(short8*)(lds + 16384 + off);
            }
            #pragma unroll
            for (int mi = 0; mi < 4; ++mi)
                #pragma unroll
                for (int ni = 0; ni < 4; ++ni)
                    acc[mi][ni] = __builtin_amdgcn_mfma_f32_16x16x32_bf16(
                        Af[mi], Bf[ni], acc[mi][ni], 0, 0, 0);
        }
    }

    // D frag: row = hi*4 + r (+16*mi), col = lo16 (+16*ni).
    if (z == 2) {
        // vT[b][dk][l] direct: r-index is contiguous in l -> pack uint2.
        if (wn == 0) {
            #pragma unroll
            for (int ni = 0; ni < 4; ++ni) {
                int n = ni * 16 + lo16;          // dk 0..63
                float bs = bias[n];
                #pragma unroll
                for (int mi = 0; mi < 4; ++mi) {
                    int mbase = m0 + wm * 64 + mi * 16 + hi * 4;
                    int b = mbase >> 10, ll = mbase & 1023;
                    uint u0 = (uint)f2bf(acc[mi][ni][0] + bs) | ((uint)f2bf(acc[mi][ni][1] + bs) << 16);
                    uint u1 = (uint)f2bf(acc[mi][ni][2] + bs) | ((uint)f2bf(acc[mi][ni][3] + bs) << 16);
                    *(uint2*)(vT + ((size_t)b * NDK + n) * NL + ll) = make_uint2(u0, u1);
                }
            }
        }
        return;
    }

    // z<2: restage C tile in LDS (bf16 [128][128] = 32KB), then short8 stores.
    __syncthreads();
    ushort* cst = (ushort*)lds;
    const int n0w = wn * 64;
    #pragma unroll
    for (int ni = 0; ni < 4; ++ni) {
        int nl = n0w + ni * 16 + lo16;
        float bs = bias[n0 + nl];
        #pragma unroll
        for (int mi = 0; mi < 4; ++mi) {
            int mlb = wm * 64 + mi * 16 + hi * 4;
            #pragma unroll
            for (int r = 0; r < 4; ++r)
                cst[(mlb + r) * 128 + nl] = f2bf((acc[mi][ni][r] + bs) * scale);
        }
    }
    __syncthreads();
    #pragma unroll
    for (int i = 0; i < 8; ++i) {
        int unit = t + 256 * i;               // 0..2047
        int row = unit >> 4, s8 = unit & 15;
        short8 v = *(short8*)(cst + row * 128 + s8 * 8);
        int m = m0 + row, n = n0 + s8 * 8;
        int b = m >> 10, ll = m & 1023, h = n >> 6, dk = n & 63;
        *(short8*)(C + (((size_t)b * NH + h) * NL + ll) * NDK + dk) = v;
    }
}

// ---------------------------------------------------------------------------
// Stage 2: MFMA attention (unchanged — verified rounds 2-4).
// ---------------------------------------------------------------------------
__global__ __launch_bounds__(256) void attn_mfma_kernel(
    const ushort* __restrict__ q_all, const ushort* __restrict__ k_all,
    const ushort* __restrict__ vT,
    float* __restrict__ attn, float* __restrict__ heads)
{
    __shared__ char raw[65536 + 640];
    float* mx   = (float*)(raw + 65536);
    float* smv  = (float*)(raw + 65536 + 256);
    float* invb = (float*)(raw + 65536 + 512);

    const int t = threadIdx.x;
    const int w = t >> 6, l = t & 63;
    const int hi = l >> 4, lo = l & 15;
    const int qh = w & 1, kh = w >> 1;
    const int q0 = blockIdx.x * 32;
    const int h  = blockIdx.y;
    const int b  = blockIdx.z;
    const size_t bh = ((size_t)b * NH + h) * NL;

    const int qr = qh * 16 + lo;
    const uint swz = ((uint)(qr & 7)) << 4;

    short8 Qb0 = *(const short8*)(q_all + (bh + q0 + qr) * NDK + hi * 8);
    short8 Qb1 = *(const short8*)(q_all + (bh + q0 + qr) * NDK + 32 + hi * 8);

    float mmax = -3.0e38f;
    for (int kt = 0; kt < 32; ++kt) {
        const int kbase = kh * 512 + kt * 16;
        short8 Ka0 = *(const short8*)(k_all + (bh + kbase + lo) * NDK + hi * 8);
        short8 Ka1 = *(const short8*)(k_all + (bh + kbase + lo) * NDK + 32 + hi * 8);
        f32x4 s = {0.f, 0.f, 0.f, 0.f};
        s = __builtin_amdgcn_mfma_f32_16x16x32_bf16(Ka0, Qb0, s, 0, 0, 0);
        s = __builtin_amdgcn_mfma_f32_16x16x32_bf16(Ka1, Qb1, s, 0, 0, 0);
        mmax = fmaxf(mmax, fmaxf(fmaxf(s[0], s[1]), fmaxf(s[2], s[3])));
        uint u0 = (uint)f2bf(s[0]) | ((uint)f2bf(s[1]) << 16);
        uint u1 = (uint)f2bf(s[2]) | ((uint)f2bf(s[3]) << 16);
        uint byteoff = (uint)qr * 2048u + ((((uint)(kbase + hi * 4)) * 2u) ^ swz);
        *(uint2*)(raw + byteoff) = make_uint2(u0, u1);
    }
    mmax = fmaxf(mmax, __shfl_xor(mmax, 16));
    mmax = fmaxf(mmax, __shfl_xor(mmax, 32));
    if (l < 16) mx[kh * 32 + qh * 16 + l] = mmax;
    __syncthreads();
    const float mf = fmaxf(mx[qr], mx[32 + qr]);

    float ssum = 0.f;
    for (int kt = 0; kt < 32; ++kt) {
        const int kbase = kh * 512 + kt * 16;
        uint byteoff = (uint)qr * 2048u + ((((uint)(kbase + hi * 4)) * 2u) ^ swz);
        uint2 v = *(uint2*)(raw + byteoff);
        float e0 = __expf(bf2f((ushort)(v.x & 0xFFFF)) - mf);
        float e1 = __expf(bf2f((ushort)(v.x >> 16)) - mf);
        float e2 = __expf(bf2f((ushort)(v.y & 0xFFFF)) - mf);
        float e3 = __expf(bf2f((ushort)(v.y >> 16)) - mf);
        ssum += (e0 + e1) + (e2 + e3);
        uint u0 = (uint)f2bf(e0) | ((uint)f2bf(e1) << 16);
        uint u1 = (uint)f2bf(e2) | ((uint)f2bf(e3) << 16);
        *(uint2*)(raw + byteoff) = make_uint2(u0, u1);
    }
    ssum += __shfl_xor(ssum, 16);
    ssum += __shfl_xor(ssum, 32);
    if (l < 16) smv[kh * 32 + qh * 16 + l] = ssum;
    __syncthreads();
    if (t < 32) invb[t] = 1.0f / (smv[t] + smv[32 + t]);
    __syncthreads();

    for (int rr = 0; rr < 32; ++rr) {
        uint byteoff = (uint)rr * 2048u + (((uint)t * 8u) ^ (((uint)(rr & 7)) << 4));
        uint2 v = *(uint2*)(raw + byteoff);
        float inv = invb[rr];
        float4 o;
        o.x = bf2f((ushort)(v.x & 0xFFFF)) * inv;
        o.y = bf2f((ushort)(v.x >> 16)) * inv;
        o.z = bf2f((ushort)(v.y & 0xFFFF)) * inv;
        o.w = bf2f((ushort)(v.y >> 16)) * inv;
        *(float4*)(attn + (((size_t)b * NL + q0 + rr) * NH + h) * NL + (size_t)t * 4) = o;
    }

    f32x4 acc0 = {0.f,0.f,0.f,0.f}, acc1 = {0.f,0.f,0.f,0.f};
    f32x4 acc2 = {0.f,0.f,0.f,0.f}, acc3 = {0.f,0.f,0.f,0.f};
    for (int kc = 0; kc < 16; ++kc) {
        const int kchunk = kh * 512 + kc * 32;
        short8 pa = *(short8*)(raw + (uint)qr * 2048u + ((((uint)(kchunk + hi * 8)) * 2u) ^ swz));
        short8 b0 = *(const short8*)(vT + ((size_t)(b * NDK +  0 + lo)) * NL + kchunk + hi * 8);
        short8 b1 = *(const short8*)(vT + ((size_t)(b * NDK + 16 + lo)) * NL + kchunk + hi * 8);
        short8 b2 = *(const short8*)(vT + ((size_t)(b * NDK + 32 + lo)) * NL + kchunk + hi * 8);
        short8 b3 = *(const short8*)(vT + ((size_t)(b * NDK + 48 + lo)) * NL + kchunk + hi * 8);
        acc0 = __builtin_amdgcn_mfma_f32_16x16x32_bf16(pa, b0, acc0, 0, 0, 0);
        acc1 = __builtin_amdgcn_mfma_f32_16x16x32_bf16(pa, b1, acc1, 0, 0, 0);
        acc2 = __builtin_amdgcn_mfma_f32_16x16x32_bf16(pa, b2, acc2, 0, 0, 0);
        acc3 = __builtin_amdgcn_mfma_f32_16x16x32_bf16(pa, b3, acc3, 0, 0, 0);
    }
    __syncthreads();
    float* pvp = (float*)raw;
    #pragma unroll
    for (int r = 0; r < 4; ++r) {
        int qq = qh * 16 + hi * 4 + r;
        pvp[(kh * 32 + qq) * 64 +  0 + lo] = acc0[r];
        pvp[(kh * 32 + qq) * 64 + 16 + lo] = acc1[r];
        pvp[(kh * 32 + qq) * 64 + 32 + lo] = acc2[r];
        pvp[(kh * 32 + qq) * 64 + 48 + lo] = acc3[r];
    }
    __syncthreads();
    #pragma unroll
    for (int i = 0; i < 8; ++i) {
        int idx = t + 256 * i;
        int qq = idx >> 6, vv = idx & 63;
        float s2 = pvp[idx] + pvp[idx + 2048];
        heads[(bh + q0 + qq) * NDK + vv] = s2 * invb[qq];
    }
}

// ---------------------------------------------------------------------------
// Stage 3: head-mean (inline) + output projection.
// ---------------------------------------------------------------------------
__global__ __launch_bounds__(256) void out_proj_kernel(
    const float* __restrict__ heads, const float* __restrict__ wo,
    const float* __restrict__ bo, float* __restrict__ out)
{
    const int t = threadIdx.x;
    const int row0 = blockIdx.x * 8;          // global row (b*1024 + l)
    const int b = row0 >> 10, l0 = row0 & 1023;
    __shared__ float hm[8][64];
    if (t < 128) {
        int r = t >> 4;
        int f4 = t & 15;
        float sx = 0.f, sy = 0.f, sz = 0.f, sw = 0.f;
        #pragma unroll
        for (int h = 0; h < 16; ++h) {
            float4 v = *(const float4*)&heads[(((size_t)b * NH + h) * NL + l0 + r) * NDK + f4 * 4];
            sx += v.x; sy += v.y; sz += v.z; sw += v.w;
        }
        float4 o; o.x = sx * 0.0625f; o.y = sy * 0.0625f; o.z = sz * 0.0625f; o.w = sw * 0.0625f;
        *(float4*)&hm[r][f4 * 4] = o;
    }
    __syncthreads();

    float acc[8][4];
    #pragma unroll
    for (int r = 0; r < 8; ++r)
        #pragma unroll
        for (int j = 0; j < 4; ++j) acc[r][j] = 0.f;

    for (int k = 0; k < 64; ++k) {
        float w0 = wo[(size_t)k * ND + t];
        float w1 = wo[(size_t)k * ND + t + 256];
        float w2 = wo[(size_t)k * ND + t + 512];
        float w3 = wo[(size_t)k * ND + t + 768];
        #pragma unroll
        for (int r = 0; r < 8; ++r) {
            float hv = hm[r][k];
            acc[r][0] += hv * w0;
            acc[r][1] += hv * w1;
            acc[r][2] += hv * w2;
            acc[r][3] += hv * w3;
        }
    }
    #pragma unroll
    for (int r = 0; r < 8; ++r) {
        out[((size_t)row0 + r) * ND + t      ] = acc[r][0] + bo[t];
        out[((size_t)row0 + r) * ND + t + 256] = acc[r][1] + bo[t + 256];
        out[((size_t)row0 + r) * ND + t + 512] = acc[r][2] + bo[t + 512];
        out[((size_t)row0 + r) * ND + t + 768] = acc[r][3] + bo[t + 768];
    }
}

// ---------------------------------------------------------------------------
extern "C" void kernel_launch(void* const* d_in, const int* in_sizes, int n_in,
                              void* d_out, int out_size, void* d_ws, size_t ws_size,
                              hipStream_t stream) {
    const float* query  = (const float*)d_in[0];
    const float* key_in = (const float*)d_in[1];
    const float* value  = (const float*)d_in[2];
    const float* wq     = (const float*)d_in[3];
    const float* bq     = (const float*)d_in[4];
    const float* wk     = (const float*)d_in[5];
    const float* bk     = (const float*)d_in[6];
    const float* wv     = (const float*)d_in[7];
    const float* bv     = (const float*)d_in[8];
    const float* wo     = (const float*)d_in[9];
    const float* bo     = (const float*)d_in[10];

    float* out  = (float*)d_out;                       // [B, L, D]
    float* attn = out + (size_t)NB * NL * ND;          // [B, L, H, L]

    ushort* wqT    = (ushort*)d_ws;                               // 2MB
    ushort* wkT    = wqT + (size_t)ND * NH * NDK;                 // 2MB
    ushort* wvT    = wkT + (size_t)ND * NH * NDK;                 // 0.26MB (128 rows)
    ushort* q_all  = wvT + (size_t)128 * ND;                      // 8.4MB
    ushort* k_all  = q_all + (size_t)NB * NH * NL * NDK;          // 8.4MB
    ushort* vT     = k_all + (size_t)NB * NH * NL * NDK;          // 0.5MB
    ushort* abf    = vT + (size_t)NB * NDK * NL;                  // 25.2MB (3 inputs bf16)
    float*  heads  = (float*)abf;   // aliases abf: disjoint lifetimes

    cvt_in_kernel<<<dim3(2048, 3), 256, 0, stream>>>(query, key_in, value, abf);
    cvtw_kernel<<<dim3(16, 33), 256, 0, stream>>>(wq, wk, wv, wqT, wkT, wvT);
    proj_gemm<<<dim3(544), 256, 0, stream>>>(
        abf, wqT, wkT, wvT, bq, bk, bv, q_all, k_all, vT);
    attn_mfma_kernel<<<dim3(32, NH, NB), 256, 0, stream>>>(
        q_all, k_all, vT, attn, heads);
    out_proj_kernel<<<dim3(NB * NL / 8), 256, 0, stream>>>(
        heads, wo, bo, out);
}

// Round 6
// 208.542 us; speedup vs baseline: 9.0628x; 1.1023x over previous
//
#include <hip/hip_runtime.h>
#include <math.h>

// Problem constants (B=4, L=1024, D=1024, H=16, DK=64)
#define NB 4
#define NL 1024
#define ND 1024
#define NH 16
#define NDK 64

typedef __attribute__((ext_vector_type(8))) short short8;
typedef __attribute__((ext_vector_type(4))) float f32x4;

__device__ inline ushort f2bf(float f) {
    uint x = __float_as_uint(f);
    x += 0x7FFFu + ((x >> 16) & 1u);   // RNE
    return (ushort)(x >> 16);
}
__device__ inline float bf2f(ushort u) { return __uint_as_float(((uint)u) << 16); }

__device__ inline void gload16(const void* g, void* l) {
    __builtin_amdgcn_global_load_lds(
        (const __attribute__((address_space(1))) void*)g,
        (__attribute__((address_space(3))) void*)l, 16, 0, 0);
}

// ---------------------------------------------------------------------------
// Input cvt: bf16(query|key|value) -> abf[y]  (y = 0,1,2)
// ---------------------------------------------------------------------------
__global__ __launch_bounds__(256) void cvt_in_kernel(
    const float* __restrict__ q, const float* __restrict__ k,
    const float* __restrict__ v, ushort* __restrict__ abf)
{
    const float* src = (blockIdx.y == 0) ? q : (blockIdx.y == 1) ? k : v;
    size_t base = ((size_t)blockIdx.x * 256 + threadIdx.x) * 8;
    float4 a = *(const float4*)(src + base);
    float4 b = *(const float4*)(src + base + 4);
    short8 o;
    o[0] = (short)f2bf(a.x); o[1] = (short)f2bf(a.y);
    o[2] = (short)f2bf(a.z); o[3] = (short)f2bf(a.w);
    o[4] = (short)f2bf(b.x); o[5] = (short)f2bf(b.y);
    o[6] = (short)f2bf(b.z); o[7] = (short)f2bf(b.w);
    *(short8*)(abf + (size_t)blockIdx.y * (NB * NL * ND) + base) = o;
}

// ---------------------------------------------------------------------------
// Weight cvt+transpose: wqT[h*64+dk][d] = bf16(wq[h][d][dk])  (B^T layout)
// ---------------------------------------------------------------------------
__global__ __launch_bounds__(256) void cvtw_kernel(
    const float* __restrict__ wq, const float* __restrict__ wk,
    const float* __restrict__ wv,
    ushort* __restrict__ wqT, ushort* __restrict__ wkT, ushort* __restrict__ wvT)
{
    __shared__ ushort tl[64][72];
    const int t = threadIdx.x;
    const int d0 = blockIdx.x * 64;
    const int y = blockIdx.y;
    const float* src; ushort* dst; int h;
    if (y < 16)      { src = wq + (size_t)y * ND * NDK;        dst = wqT; h = y; }
    else if (y < 32) { src = wk + (size_t)(y - 16) * ND * NDK; dst = wkT; h = y - 16; }
    else             { src = wv;                               dst = wvT; h = 0; }

    int r = t >> 2, c0 = (t & 3) * 16;
    const float* s = src + (size_t)(d0 + r) * NDK + c0;
    #pragma unroll
    for (int j = 0; j < 16; j += 4) {
        float4 v = *(const float4*)(s + j);
        tl[c0 + j + 0][r] = f2bf(v.x);
        tl[c0 + j + 1][r] = f2bf(v.y);
        tl[c0 + j + 2][r] = f2bf(v.z);
        tl[c0 + j + 3][r] = f2bf(v.w);
    }
    __syncthreads();
    int vv = t >> 2, lc = (t & 3) * 16;
    ushort* d = dst + ((size_t)h * 64 + vv) * ND + d0 + lc;
    #pragma unroll
    for (int j = 0; j < 16; j += 8) {
        short8 o;
        #pragma unroll
        for (int e = 0; e < 8; ++e) o[e] = (short)tl[vv][lc + j + e];
        *(short8*)(d + j) = o;
    }
    if (y == 32) {
        ushort* zp = wvT + ((size_t)(64 + (t >> 2))) * ND + d0 + (t & 3) * 16;
        short8 z8 = {0,0,0,0,0,0,0,0};
        *(short8*)(zp) = z8;
        *(short8*)(zp + 8) = z8;
    }
}

// ---------------------------------------------------------------------------
// MFMA projection GEMM. 128x128 tile, BK=64, 4 waves (2x2 of 64x64).
// 2-phase pipelined: double-buffered LDS, STAGE(kt+1) via global_load_lds
// issued before ds_read+MFMA of kt; single __syncthreads per iter (its
// vmcnt(0) drain covers the prefetch). Source pre-swizzled -> LDS content
// XOR-swizzled (byte ^= (row&7)<<4); readers unchanged.
// ---------------------------------------------------------------------------
__global__ __launch_bounds__(256) void proj_gemm(
    const ushort* __restrict__ abf,
    const ushort* __restrict__ wqT, const ushort* __restrict__ wkT,
    const ushort* __restrict__ wvT,
    const float* __restrict__ bq, const float* __restrict__ bk,
    const float* __restrict__ bv,
    ushort* __restrict__ q_all, ushort* __restrict__ k_all,
    ushort* __restrict__ vT)
{
    __shared__ char lds[65536];   // buf c at c*32768: A [128][64] @0, B @16384

    int id = blockIdx.x;
    int wg = (id & 7) * 68 + (id >> 3);   // 544 = 8 XCDs x 68, bijective
    int z, mt, nt;
    if (wg < 512) { z = wg >> 8; int rem = wg & 255; mt = rem >> 3; nt = rem & 7; }
    else          { z = 2; mt = wg - 512; nt = 0; }

    const ushort* A; const ushort* Bw; const float* bias; float scale;
    if (z == 0)      { A = abf;                    Bw = wqT; bias = bq; scale = 0.125f; }
    else if (z == 1) { A = abf + NB * NL * ND;     Bw = wkT; bias = bk; scale = 1.0f; }
    else             { A = abf + 2 * NB * NL * ND; Bw = wvT; bias = bv; scale = 1.0f; }
    ushort* C = (z == 0) ? q_all : k_all;

    const int t = threadIdx.x;
    const int w = t >> 6, l = t & 63;
    const int lo16 = l & 15, hi = l >> 4;
    const int wm = w >> 1, wn = w & 1;
    const int m0 = mt * 128, n0 = nt * 128;

    f32x4 acc[4][4];
    #pragma unroll
    for (int mi = 0; mi < 4; ++mi)
        #pragma unroll
        for (int ni = 0; ni < 4; ++ni) acc[mi][ni] = (f32x4){0.f, 0.f, 0.f, 0.f};

    // stager geometry: slab s = w*4+i covers LDS bytes [s*1024,(s+1)*1024);
    // lane l -> physical byte s*1024 + l*16 = row s*8+(l>>3), inv-swz col.
    int rS[4]; uint cS[4];
    #pragma unroll
    for (int i = 0; i < 4; ++i) {
        int s = w * 4 + i;
        int row = s * 8 + (l >> 3);
        rS[i] = row;
        cS[i] = (((uint)(l & 7)) * 16u) ^ (((uint)(row & 7)) << 4);
    }

    // prologue: stage kt=0 into buf0
    #pragma unroll
    for (int i = 0; i < 4; ++i) {
        int s = w * 4 + i;
        gload16(A  + (size_t)(m0 + rS[i]) * ND + (cS[i] >> 1), lds + s * 1024);
        gload16(Bw + (size_t)(n0 + rS[i]) * ND + (cS[i] >> 1), lds + 16384 + s * 1024);
    }
    __syncthreads();

    int cur = 0;
    for (int kt = 0; kt < 16; ++kt) {
        if (kt < 15) {
            const int k1 = (kt + 1) * 64;
            const int nb = (cur ^ 1) * 32768;
            #pragma unroll
            for (int i = 0; i < 4; ++i) {
                int s = w * 4 + i;
                gload16(A  + (size_t)(m0 + rS[i]) * ND + k1 + (cS[i] >> 1), lds + nb + s * 1024);
                gload16(Bw + (size_t)(n0 + rS[i]) * ND + k1 + (cS[i] >> 1), lds + nb + 16384 + s * 1024);
            }
        }
        const int cb = cur * 32768;
        #pragma unroll
        for (int ks = 0; ks < 2; ++ks) {
            short8 Af[4], Bf[4];
            #pragma unroll
            for (int mi = 0; mi < 4; ++mi) {
                int row = wm * 64 + mi * 16 + lo16;
                uint off = ((uint)row * 128u + (uint)(ks * 64 + hi * 16)) ^ (((uint)(row & 7)) << 4);
                Af[mi] = *(short8*)(lds + cb + off);
            }
            #pragma unroll
            for (int ni = 0; ni < 4; ++ni) {
                int row = wn * 64 + ni * 16 + lo16;
                uint off = ((uint)row * 128u + (uint)(ks * 64 + hi * 16)) ^ (((uint)(row & 7)) << 4);
                Bf[ni] = *(short8*)(lds + cb + 16384 + off);
            }
            #pragma unroll
            for (int mi = 0; mi < 4; ++mi)
                #pragma unroll
                for (int ni = 0; ni < 4; ++ni)
                    acc[mi][ni] = __builtin_amdgcn_mfma_f32_16x16x32_bf16(
                        Af[mi], Bf[ni], acc[mi][ni], 0, 0, 0);
        }
        __syncthreads();   // drains vmcnt (prefetch landed) + readers done
        cur ^= 1;
    }

    // D frag: row = hi*4 + r (+16*mi), col = lo16 (+16*ni).
    if (z == 2) {
        if (wn == 0) {
            #pragma unroll
            for (int ni = 0; ni < 4; ++ni) {
                int n = ni * 16 + lo16;          // dk 0..63
                float bs = bias[n];
                #pragma unroll
                for (int mi = 0; mi < 4; ++mi) {
                    int mbase = m0 + wm * 64 + mi * 16 + hi * 4;
                    int b = mbase >> 10, ll = mbase & 1023;
                    uint u0 = (uint)f2bf(acc[mi][ni][0] + bs) | ((uint)f2bf(acc[mi][ni][1] + bs) << 16);
                    uint u1 = (uint)f2bf(acc[mi][ni][2] + bs) | ((uint)f2bf(acc[mi][ni][3] + bs) << 16);
                    *(uint2*)(vT + ((size_t)b * NDK + n) * NL + ll) = make_uint2(u0, u1);
                }
            }
        }
        return;
    }

    // z<2: restage C tile in LDS (bf16 [128][128] = 32KB), then short8 stores.
    ushort* cst = (ushort*)lds;
    const int n0w = wn * 64;
    #pragma unroll
    for (int ni = 0; ni < 4; ++ni) {
        int nl = n0w + ni * 16 + lo16;
        float bs = bias[n0 + nl];
        #pragma unroll
        for (int mi = 0; mi < 4; ++mi) {
            int mlb = wm * 64 + mi * 16 + hi * 4;
            #pragma unroll
            for (int r = 0; r < 4; ++r)
                cst[(mlb + r) * 128 + nl] = f2bf((acc[mi][ni][r] + bs) * scale);
        }
    }
    __syncthreads();
    #pragma unroll
    for (int i = 0; i < 8; ++i) {
        int unit = t + 256 * i;               // 0..2047
        int row = unit >> 4, s8 = unit & 15;
        short8 v = *(short8*)(cst + row * 128 + s8 * 8);
        int m = m0 + row, n = n0 + s8 * 8;
        int b = m >> 10, ll = m & 1023, h = n >> 6, dk = n & 63;
        *(short8*)(C + (((size_t)b * NH + h) * NL + ll) * NDK + dk) = v;
    }
}

// ---------------------------------------------------------------------------
// Stage 2: MFMA attention. One block per (b, h, 16-q-row tile). 4 waves,
// wave w owns k-quarter [w*256, (w+1)*256). Scores bf16 in LDS [16][1024],
// XOR-swizzled (row&7)<<4. Softmax stats and PV combine across 4 waves.
// LDS 32.6KB -> 4 blocks/CU (16 waves/CU).
// ---------------------------------------------------------------------------
__global__ __launch_bounds__(256) void attn_mfma_kernel(
    const ushort* __restrict__ q_all, const ushort* __restrict__ k_all,
    const ushort* __restrict__ vT,
    float* __restrict__ attn, float* __restrict__ heads)
{
    __shared__ char raw[32768 + 576];
    float* mx   = (float*)(raw + 32768);         // [4][16]
    float* smv  = (float*)(raw + 32768 + 256);   // [4][16]
    float* invb = (float*)(raw + 32768 + 512);   // [16]

    const int t = threadIdx.x;
    const int kh = t >> 6, l = t & 63;           // wave = k-quarter
    const int hi = l >> 4, lo = l & 15;
    const int q0 = blockIdx.x * 16;
    const int h  = blockIdx.y;
    const int b  = blockIdx.z;
    const size_t bh = ((size_t)b * NH + h) * NL;

    const int qr = lo;                           // score row owned by lane's D-col
    const uint swz = ((uint)(qr & 7)) << 4;

    short8 Qb0 = *(const short8*)(q_all + (bh + q0 + qr) * NDK + hi * 8);
    short8 Qb1 = *(const short8*)(q_all + (bh + q0 + qr) * NDK + 32 + hi * 8);

    // ---- QK^T: raw scores -> LDS (bf16), online per-lane max ----
    float mmax = -3.0e38f;
    for (int kt = 0; kt < 16; ++kt) {
        const int kbase = kh * 256 + kt * 16;
        short8 Ka0 = *(const short8*)(k_all + (bh + kbase + lo) * NDK + hi * 8);
        short8 Ka1 = *(const short8*)(k_all + (bh + kbase + lo) * NDK + 32 + hi * 8);
        f32x4 s = {0.f, 0.f, 0.f, 0.f};
        s = __builtin_amdgcn_mfma_f32_16x16x32_bf16(Ka0, Qb0, s, 0, 0, 0);
        s = __builtin_amdgcn_mfma_f32_16x16x32_bf16(Ka1, Qb1, s, 0, 0, 0);
        mmax = fmaxf(mmax, fmaxf(fmaxf(s[0], s[1]), fmaxf(s[2], s[3])));
        uint u0 = (uint)f2bf(s[0]) | ((uint)f2bf(s[1]) << 16);
        uint u1 = (uint)f2bf(s[2]) | ((uint)f2bf(s[3]) << 16);
        uint byteoff = (uint)qr * 2048u + ((((uint)(kbase + hi * 4)) * 2u) ^ swz);
        *(uint2*)(raw + byteoff) = make_uint2(u0, u1);
    }
    mmax = fmaxf(mmax, __shfl_xor(mmax, 16));
    mmax = fmaxf(mmax, __shfl_xor(mmax, 32));
    if (l < 16) mx[kh * 16 + l] = mmax;
    __syncthreads();
    const float mf = fmaxf(fmaxf(mx[qr], mx[16 + qr]), fmaxf(mx[32 + qr], mx[48 + qr]));

    // ---- exp pass ----
    float ssum = 0.f;
    for (int kt = 0; kt < 16; ++kt) {
        const int kbase = kh * 256 + kt * 16;
        uint byteoff = (uint)qr * 2048u + ((((uint)(kbase + hi * 4)) * 2u) ^ swz);
        uint2 v = *(uint2*)(raw + byteoff);
        float e0 = __expf(bf2f((ushort)(v.x & 0xFFFF)) - mf);
        float e1 = __expf(bf2f((ushort)(v.x >> 16)) - mf);
        float e2 = __expf(bf2f((ushort)(v.y & 0xFFFF)) - mf);
        float e3 = __expf(bf2f((ushort)(v.y >> 16)) - mf);
        ssum += (e0 + e1) + (e2 + e3);
        uint u0 = (uint)f2bf(e0) | ((uint)f2bf(e1) << 16);
        uint u1 = (uint)f2bf(e2) | ((uint)f2bf(e3) << 16);
        *(uint2*)(raw + byteoff) = make_uint2(u0, u1);
    }
    ssum += __shfl_xor(ssum, 16);
    ssum += __shfl_xor(ssum, 32);
    if (l < 16) smv[kh * 16 + l] = ssum;
    __syncthreads();
    if (t < 16) invb[t] = 1.0f / (smv[t] + smv[16 + t] + smv[32 + t] + smv[48 + t]);
    __syncthreads();

    // ---- write normalized attn rows: [B, Lq, H, Lk], float4 coalesced ----
    for (int rr = 0; rr < 16; ++rr) {
        uint byteoff = (uint)rr * 2048u + (((uint)t * 8u) ^ (((uint)(rr & 7)) << 4));
        uint2 v = *(uint2*)(raw + byteoff);
        float inv = invb[rr];
        float4 o;
        o.x = bf2f((ushort)(v.x & 0xFFFF)) * inv;
        o.y = bf2f((ushort)(v.x >> 16)) * inv;
        o.z = bf2f((ushort)(v.y & 0xFFFF)) * inv;
        o.w = bf2f((ushort)(v.y >> 16)) * inv;
        *(float4*)(attn + (((size_t)b * NL + q0 + rr) * NH + h) * NL + (size_t)t * 4) = o;
    }

    // ---- PV: per-wave k-quarter partials ----
    f32x4 acc0 = {0.f,0.f,0.f,0.f}, acc1 = {0.f,0.f,0.f,0.f};
    f32x4 acc2 = {0.f,0.f,0.f,0.f}, acc3 = {0.f,0.f,0.f,0.f};
    for (int kc = 0; kc < 8; ++kc) {
        const int kchunk = kh * 256 + kc * 32;
        short8 pa = *(short8*)(raw + (uint)qr * 2048u + ((((uint)(kchunk + hi * 8)) * 2u) ^ swz));
        short8 b0 = *(const short8*)(vT + ((size_t)(b * NDK +  0 + lo)) * NL + kchunk + hi * 8);
        short8 b1 = *(const short8*)(vT + ((size_t)(b * NDK + 16 + lo)) * NL + kchunk + hi * 8);
        short8 b2 = *(const short8*)(vT + ((size_t)(b * NDK + 32 + lo)) * NL + kchunk + hi * 8);
        short8 b3 = *(const short8*)(vT + ((size_t)(b * NDK + 48 + lo)) * NL + kchunk + hi * 8);
        acc0 = __builtin_amdgcn_mfma_f32_16x16x32_bf16(pa, b0, acc0, 0, 0, 0);
        acc1 = __builtin_amdgcn_mfma_f32_16x16x32_bf16(pa, b1, acc1, 0, 0, 0);
        acc2 = __builtin_amdgcn_mfma_f32_16x16x32_bf16(pa, b2, acc2, 0, 0, 0);
        acc3 = __builtin_amdgcn_mfma_f32_16x16x32_bf16(pa, b3, acc3, 0, 0, 0);
    }
    __syncthreads();   // all waves done READING scores before aliasing writes
    float* pvp = (float*)raw;   // [4 kh][16 q][64 v] f32 = 16KB, aliases scores
    #pragma unroll
    for (int r = 0; r < 4; ++r) {
        int qq = hi * 4 + r;
        pvp[(kh * 16 + qq) * 64 +  0 + lo] = acc0[r];
        pvp[(kh * 16 + qq) * 64 + 16 + lo] = acc1[r];
        pvp[(kh * 16 + qq) * 64 + 32 + lo] = acc2[r];
        pvp[(kh * 16 + qq) * 64 + 48 + lo] = acc3[r];
    }
    __syncthreads();
    #pragma unroll
    for (int i = 0; i < 4; ++i) {
        int idx = t + 256 * i;              // 0..1023 = q*64 + v
        int qq = idx >> 6, vv = idx & 63;
        float s4 = pvp[idx] + pvp[idx + 1024] + pvp[idx + 2048] + pvp[idx + 3072];
        heads[(bh + q0 + qq) * NDK + vv] = s4 * invb[qq];
    }
}

// ---------------------------------------------------------------------------
// Stage 3: head-mean (inline) + output projection.
// ---------------------------------------------------------------------------
__global__ __launch_bounds__(256) void out_proj_kernel(
    const float* __restrict__ heads, const float* __restrict__ wo,
    const float* __restrict__ bo, float* __restrict__ out)
{
    const int t = threadIdx.x;
    const int row0 = blockIdx.x * 8;          // global row (b*1024 + l)
    const int b = row0 >> 10, l0 = row0 & 1023;
    __shared__ float hm[8][64];
    if (t < 128) {
        int r = t >> 4;
        int f4 = t & 15;
        float sx = 0.f, sy = 0.f, sz = 0.f, sw = 0.f;
        #pragma unroll
        for (int h = 0; h < 16; ++h) {
            float4 v = *(const float4*)&heads[(((size_t)b * NH + h) * NL + l0 + r) * NDK + f4 * 4];
            sx += v.x; sy += v.y; sz += v.z; sw += v.w;
        }
        float4 o; o.x = sx * 0.0625f; o.y = sy * 0.0625f; o.z = sz * 0.0625f; o.w = sw * 0.0625f;
        *(float4*)&hm[r][f4 * 4] = o;
    }
    __syncthreads();

    float acc[8][4];
    #pragma unroll
    for (int r = 0; r < 8; ++r)
        #pragma unroll
        for (int j = 0; j < 4; ++j) acc[r][j] = 0.f;

    for (int k = 0; k < 64; ++k) {
        float w0 = wo[(size_t)k * ND + t];
        float w1 = wo[(size_t)k * ND + t + 256];
        float w2 = wo[(size_t)k * ND + t + 512];
        float w3 = wo[(size_t)k * ND + t + 768];
        #pragma unroll
        for (int r = 0; r < 8; ++r) {
            float hv = hm[r][k];
            acc[r][0] += hv * w0;
            acc[r][1] += hv * w1;
            acc[r][2] += hv * w2;
            acc[r][3] += hv * w3;
        }
    }
    #pragma unroll
    for (int r = 0; r < 8; ++r) {
        out[((size_t)row0 + r) * ND + t      ] = acc[r][0] + bo[t];
        out[((size_t)row0 + r) * ND + t + 256] = acc[r][1] + bo[t + 256];
        out[((size_t)row0 + r) * ND + t + 512] = acc[r][2] + bo[t + 512];
        out[((size_t)row0 + r) * ND + t + 768] = acc[r][3] + bo[t + 768];
    }
}

// ---------------------------------------------------------------------------
extern "C" void kernel_launch(void* const* d_in, const int* in_sizes, int n_in,
                              void* d_out, int out_size, void* d_ws, size_t ws_size,
                              hipStream_t stream) {
    const float* query  = (const float*)d_in[0];
    const float* key_in = (const float*)d_in[1];
    const float* value  = (const float*)d_in[2];
    const float* wq     = (const float*)d_in[3];
    const float* bq     = (const float*)d_in[4];
    const float* wk     = (const float*)d_in[5];
    const float* bk     = (const float*)d_in[6];
    const float* wv     = (const float*)d_in[7];
    const float* bv     = (const float*)d_in[8];
    const float* wo     = (const float*)d_in[9];
    const float* bo     = (const float*)d_in[10];

    float* out  = (float*)d_out;                       // [B, L, D]
    float* attn = out + (size_t)NB * NL * ND;          // [B, L, H, L]

    ushort* wqT    = (ushort*)d_ws;                               // 2MB
    ushort* wkT    = wqT + (size_t)ND * NH * NDK;                 // 2MB
    ushort* wvT    = wkT + (size_t)ND * NH * NDK;                 // 0.26MB (128 rows)
    ushort* q_all  = wvT + (size_t)128 * ND;                      // 8.4MB
    ushort* k_all  = q_all + (size_t)NB * NH * NL * NDK;          // 8.4MB
    ushort* vT     = k_all + (size_t)NB * NH * NL * NDK;          // 0.5MB
    ushort* abf    = vT + (size_t)NB * NDK * NL;                  // 25.2MB (3 inputs bf16)
    float*  heads  = (float*)abf;   // aliases abf: disjoint lifetimes

    cvt_in_kernel<<<dim3(2048, 3), 256, 0, stream>>>(query, key_in, value, abf);
    cvtw_kernel<<<dim3(16, 33), 256, 0, stream>>>(wq, wk, wv, wqT, wkT, wvT);
    proj_gemm<<<dim3(544), 256, 0, stream>>>(
        abf, wqT, wkT, wvT, bq, bk, bv, q_all, k_all, vT);
    attn_mfma_kernel<<<dim3(64, NH, NB), 256, 0, stream>>>(
        q_all, k_all, vT, attn, heads);
    out_proj_kernel<<<dim3(NB * NL / 8), 256, 0, stream>>>(
        heads, wo, bo, out);
}